// Round 1
// baseline (6602.225 us; speedup 1.0000x reference)
//
#include <hip/hip_runtime.h>
#include <math.h>

// ---------------------------------------------------------------------------
// Molecular GNN forward (GATv2 x6 + ring encoder + mol encoder), f32 baseline.
// Phases:
//   1) h = x@Wx+b ; e = edge_attr@We+b ; self-loop edges with mean incoming e
//   2) 6x GATv2: xl,xr,ewe GEMMs -> edge score -> segment softmax -> scatter
//   3) ring gather -> encoder(S=6,nh=2) -> abs-argmax pick
//   4) seq assemble -> encoder(S=139,nh=4) -> d_out ; ones for not_padded
// Workspace arena (bytes), peak ~226MB:
//   GAT : H(0..16M) HN(16..32M) XL(32..48M) XR(48..64M) EALL(64..144M)
//         EWE(144..224M) small(224M..) RVEC(225M..226M)
//   ring: reuses HN/XL/XR/EALL region ; mol: reuses 16..140M region
// ---------------------------------------------------------------------------

#define DEV __device__ __forceinline__

constexpr int NN   = 8192;     // nodes
constexpr int EE   = 32768;    // edges
constexpr int ENL  = EE + NN;  // edges + self loops = 40960
constexpr int D    = 512;
constexpr int RGS  = 512;      // rings
constexpr int RS   = 6;        // ring size
constexpr int BMOL = 64;
constexpr int SEQS = 139;
constexpr int NSEQ = BMOL * SEQS;  // 8896
constexpr int DFF  = 2048;

DEV float wsum(float v) {
    for (int o = 32; o > 0; o >>= 1) v += __shfl_xor(v, o, 64);
    return v;
}
DEV float wmax(float v) {
    for (int o = 32; o > 0; o >>= 1) v = fmaxf(v, __shfl_xor(v, o, 64));
    return v;
}

DEV void atomicMaxF(float* addr, float val) {
    unsigned int* ua = (unsigned int*)addr;
    unsigned int old = *ua;
    while (true) {
        float fold = __uint_as_float(old);
        if (fold >= val) break;
        unsigned int assumed = old;
        old = atomicCAS(ua, assumed, __float_as_uint(val));
        if (old == assumed) break;
    }
}

// ---------------------------------------------------------------------------
// Generic f32 GEMM: C[M,N] = A[M,K] @ B[K,N] (+bias) (+relu)
// Requires M%64==0, N%64==0, K%16==0. Block 256 thr, 64x64 tile, 4x4/thread.
// flags: 1 = add bias[N], 2 = relu
// ---------------------------------------------------------------------------
__global__ __launch_bounds__(256) void gemm_f32(
    const float* __restrict__ A, const float* __restrict__ B,
    const float* __restrict__ bias, float* __restrict__ C,
    int M, int Nn, int K, int flags)
{
    __shared__ float As[16][64];
    __shared__ float Bs[16][64];
    const int tid = threadIdx.x;
    const int tx = tid & 15, ty = tid >> 4;
    const int m0 = blockIdx.x * 64, n0 = blockIdx.y * 64;

    const int arow  = tid >> 2;          // 0..63
    const int acolb = (tid & 3) * 4;     // 0,4,8,12
    const int brow  = tid >> 4;          // 0..15
    const int bcol  = (tid & 15) * 4;    // 0..60

    float acc[4][4] = {};

    for (int k0 = 0; k0 < K; k0 += 16) {
        float4 av = *(const float4*)&A[(size_t)(m0 + arow) * K + k0 + acolb];
        float4 bv = *(const float4*)&B[(size_t)(k0 + brow) * Nn + n0 + bcol];
        As[acolb + 0][arow] = av.x;
        As[acolb + 1][arow] = av.y;
        As[acolb + 2][arow] = av.z;
        As[acolb + 3][arow] = av.w;
        *(float4*)&Bs[brow][bcol] = bv;
        __syncthreads();
#pragma unroll
        for (int k = 0; k < 16; ++k) {
            float4 a = *(const float4*)&As[k][ty * 4];
            float4 b = *(const float4*)&Bs[k][tx * 4];
            float aa[4] = {a.x, a.y, a.z, a.w};
            float bb[4] = {b.x, b.y, b.z, b.w};
#pragma unroll
            for (int i = 0; i < 4; ++i)
#pragma unroll
                for (int j = 0; j < 4; ++j) acc[i][j] += aa[i] * bb[j];
        }
        __syncthreads();
    }

#pragma unroll
    for (int i = 0; i < 4; ++i) {
        size_t row = (size_t)(m0 + ty * 4 + i);
        float4 o = make_float4(acc[i][0], acc[i][1], acc[i][2], acc[i][3]);
        if (flags & 1) {
            const float* bp = bias + n0 + tx * 4;
            o.x += bp[0]; o.y += bp[1]; o.z += bp[2]; o.w += bp[3];
        }
        if (flags & 2) {
            o.x = fmaxf(o.x, 0.f); o.y = fmaxf(o.y, 0.f);
            o.z = fmaxf(o.z, 0.f); o.w = fmaxf(o.w, 0.f);
        }
        *(float4*)&C[row * Nn + n0 + tx * 4] = o;
    }
}

// ---------------------------------------------------------------------------
// Row LayerNorm (D=512), wave per row. out = [relu?] LN(x (+res) (+bias)) *g+b
// flags: 1 = relu, 2 = do LN.  (flags==0: out = x+bias passthrough)
// ---------------------------------------------------------------------------
__global__ __launch_bounds__(256) void ln_rows(
    const float* __restrict__ x, const float* __restrict__ res,
    const float* __restrict__ bias, const float* __restrict__ g,
    const float* __restrict__ be, float* __restrict__ out, int rows, int flags)
{
    int r = blockIdx.x * 4 + (threadIdx.x >> 6);
    if (r >= rows) return;
    int lane = threadIdx.x & 63;
    size_t base = (size_t)r * D;
    float v[8];
#pragma unroll
    for (int i = 0; i < 8; ++i) {
        int d = lane + i * 64;
        float t = x[base + d];
        if (res)  t += res[base + d];
        if (bias) t += bias[d];
        v[i] = t;
    }
    if (flags & 2) {
        float s = 0;
#pragma unroll
        for (int i = 0; i < 8; ++i) s += v[i];
        float mu = wsum(s) * (1.f / 512.f);
        float q = 0;
#pragma unroll
        for (int i = 0; i < 8; ++i) { float d0 = v[i] - mu; q += d0 * d0; }
        float inv = rsqrtf(wsum(q) * (1.f / 512.f) + 1e-5f);
#pragma unroll
        for (int i = 0; i < 8; ++i) {
            int d = lane + i * 64;
            float o = (v[i] - mu) * inv * g[d] + be[d];
            if (flags & 1) o = fmaxf(o, 0.f);
            out[base + d] = o;
        }
    } else {
#pragma unroll
        for (int i = 0; i < 8; ++i) {
            int d = lane + i * 64;
            float o = v[i];
            if (flags & 1) o = fmaxf(o, 0.f);
            out[base + d] = o;
        }
    }
}

__global__ void fill_f32(float* p, float v, int n) {
    int i = blockIdx.x * 256 + threadIdx.x;
    if (i < n) p[i] = v;
}

// ---------------------------------------------------------------------------
// Self-loop edge attr (mean incoming)
// ---------------------------------------------------------------------------
__global__ void deg_count(const int* __restrict__ ei, float* __restrict__ deg) {
    int e = blockIdx.x * 256 + threadIdx.x;
    if (e >= EE) return;
    atomicAdd(&deg[ei[EE + e]], 1.0f);
}

__global__ __launch_bounds__(256) void loop_acc(
    const float* __restrict__ eattr, const int* __restrict__ ei,
    float* __restrict__ loopp)  // loopp = e_all + EE*D
{
    int e = blockIdx.x * 4 + (threadIdx.x >> 6);
    if (e >= EE) return;
    int lane = threadIdx.x & 63;
    int dn = ei[EE + e];
#pragma unroll
    for (int i = 0; i < 8; ++i) {
        int d = lane + i * 64;
        atomicAdd(&loopp[(size_t)dn * D + d], eattr[(size_t)e * D + d]);
    }
}

__global__ __launch_bounds__(256) void loop_scale(
    float* __restrict__ loopp, const float* __restrict__ deg)
{
    int n = blockIdx.x * 4 + (threadIdx.x >> 6);
    if (n >= NN) return;
    int lane = threadIdx.x & 63;
    float w = 1.0f / fmaxf(deg[n], 1.0f);
#pragma unroll
    for (int i = 0; i < 8; ++i) loopp[(size_t)n * D + lane + i * 64] *= w;
}

// ---------------------------------------------------------------------------
// GATv2 edge machinery
// ---------------------------------------------------------------------------
DEV void edge_nodes(int e, const int* ei, int& s, int& dn) {
    if (e < EE) { s = ei[e]; dn = ei[EE + e]; }
    else        { s = dn = e - EE; }
}

__global__ __launch_bounds__(256) void gat_score(
    const float* __restrict__ xl, const float* __restrict__ xr,
    const float* __restrict__ ewe, const int* __restrict__ ei,
    const float* __restrict__ att, float* __restrict__ score)
{
    int e = blockIdx.x * 4 + (threadIdx.x >> 6);
    if (e >= ENL) return;
    int lane = threadIdx.x & 63;
    int s, dn;
    edge_nodes(e, ei, s, dn);
    float acc = 0;
#pragma unroll
    for (int i = 0; i < 8; ++i) {
        int d = lane + i * 64;
        float m = xl[(size_t)s * D + d] + xr[(size_t)dn * D + d] + ewe[(size_t)e * D + d];
        m = m > 0.f ? m : 0.2f * m;   // leaky relu 0.2
        acc += att[d] * m;
    }
    acc = wsum(acc);
    if (lane == 0) score[e] = acc;
}

__global__ void seg_max_k(const float* __restrict__ score, const int* __restrict__ ei,
                          float* __restrict__ segmax) {
    int e = blockIdx.x * 256 + threadIdx.x;
    if (e >= ENL) return;
    int s, dn; edge_nodes(e, ei, s, dn);
    atomicMaxF(&segmax[dn], score[e]);
}

__global__ void seg_exp_k(const float* __restrict__ score, const int* __restrict__ ei,
                          const float* __restrict__ segmax, float* __restrict__ expv,
                          float* __restrict__ segsum) {
    int e = blockIdx.x * 256 + threadIdx.x;
    if (e >= ENL) return;
    int s, dn; edge_nodes(e, ei, s, dn);
    float x = expf(score[e] - segmax[dn]);
    expv[e] = x;
    atomicAdd(&segsum[dn], x);
}

__global__ __launch_bounds__(256) void gat_scatter(
    const float* __restrict__ xl, const int* __restrict__ ei,
    const float* __restrict__ expv, const float* __restrict__ segsum,
    float* __restrict__ outp)
{
    int e = blockIdx.x * 4 + (threadIdx.x >> 6);
    if (e >= ENL) return;
    int lane = threadIdx.x & 63;
    int s, dn; edge_nodes(e, ei, s, dn);
    float w = expv[e] / segsum[dn];
#pragma unroll
    for (int i = 0; i < 8; ++i) {
        int d = lane + i * 64;
        atomicAdd(&outp[(size_t)dn * D + d], w * xl[(size_t)s * D + d]);
    }
}

// ---------------------------------------------------------------------------
// Ring / mol helpers
// ---------------------------------------------------------------------------
__global__ void gather_rows(const float* __restrict__ src, const int* __restrict__ idx,
                            float* __restrict__ dst, int nrows) {
    int i = blockIdx.x * 256 + threadIdx.x;
    int r = i >> 9;
    if (r >= nrows) return;
    dst[i] = src[(size_t)idx[r] * D + (i & 511)];
}

// ring attention: nh=2, dh=256, S=6. block per (ring, head)
__global__ __launch_bounds__(256) void ring_attn(
    const float* __restrict__ q, const float* __restrict__ k,
    const float* __restrict__ v, float* __restrict__ o)
{
    int rh = blockIdx.x, r = rh >> 1, hh = rh & 1;
    __shared__ float qs[RS * 256], ks[RS * 256], vs[RS * 256];
    __shared__ float sc[36], pr[36];
    int tid = threadIdx.x;
    size_t base = (size_t)r * RS * D + hh * 256;
    for (int i = tid; i < RS * 256; i += 256) {
        int si = i >> 8, d = i & 255;
        size_t g = base + (size_t)si * D + d;
        qs[i] = q[g]; ks[i] = k[g]; vs[i] = v[g];
    }
    __syncthreads();
    if (tid < 36) {
        int i = tid / 6, j = tid % 6;
        float a = 0;
        for (int d = 0; d < 256; ++d) a += qs[i * 256 + d] * ks[j * 256 + d];
        sc[tid] = a * (1.f / 16.f);   // 1/sqrt(256)
    }
    __syncthreads();
    if (tid < 6) {
        float mx = -1e30f;
        for (int j = 0; j < 6; ++j) mx = fmaxf(mx, sc[tid * 6 + j]);
        float p[6], s = 0;
        for (int j = 0; j < 6; ++j) { p[j] = expf(sc[tid * 6 + j] - mx); s += p[j]; }
        for (int j = 0; j < 6; ++j) pr[tid * 6 + j] = p[j] / s;
    }
    __syncthreads();
    for (int i = tid; i < RS * 256; i += 256) {
        int si = i >> 8, d = i & 255;
        float a = 0;
        for (int j = 0; j < 6; ++j) a += pr[si * 6 + j] * vs[j * 256 + d];
        o[base + (size_t)si * D + d] = a;
    }
}

// mol attention: nh=4, dh=128, S=139. block per (b, head)
__global__ __launch_bounds__(256) void mol_attn(
    const float* __restrict__ q, const float* __restrict__ k,
    const float* __restrict__ v, float* __restrict__ o)
{
    int bh = blockIdx.x, b = bh >> 2, hh = bh & 3;
    __shared__ float qi[128];
    __shared__ float sc[SEQS];
    __shared__ float red[4];
    __shared__ float smaxs, ssums;
    int tid = threadIdx.x;
    size_t base = (size_t)b * SEQS * D + hh * 128;
    for (int i = 0; i < SEQS; ++i) {
        if (tid < 128) qi[tid] = q[base + (size_t)i * D + tid];
        __syncthreads();
        float val = -1e30f;
        if (tid < SEQS) {
            const float* kp = &k[base + (size_t)tid * D];
            float a = 0;
            for (int d = 0; d < 128; ++d) a += qi[d] * kp[d];
            a *= 0.08838834764831845f;  // 1/sqrt(128)
            sc[tid] = a; val = a;
        }
        float m = wmax(val);
        if ((tid & 63) == 0) red[tid >> 6] = m;
        __syncthreads();
        if (tid == 0) smaxs = fmaxf(fmaxf(red[0], red[1]), fmaxf(red[2], red[3]));
        __syncthreads();
        float pv = 0;
        if (tid < SEQS) { pv = expf(sc[tid] - smaxs); sc[tid] = pv; }
        float s = wsum(pv);
        if ((tid & 63) == 0) red[tid >> 6] = s;
        __syncthreads();
        if (tid == 0) ssums = red[0] + red[1] + red[2] + red[3];
        __syncthreads();
        if (tid < 128) {
            const float* vp = &v[base + tid];
            float a = 0;
            for (int j = 0; j < SEQS; ++j) a += sc[j] * vp[(size_t)j * D];
            o[base + (size_t)i * D + tid] = a / ssums;
        }
        __syncthreads();
    }
}

// per (ring, channel) abs-argmax gather over S=6
__global__ void ring_pick(const float* __restrict__ t, float* __restrict__ rv) {
    int i = blockIdx.x * 256 + threadIdx.x;
    if (i >= RGS * D) return;
    int r = i >> 9, d = i & 511;
    const float* p = &t[(size_t)r * RS * D + d];
    float best = p[0], ba = fabsf(best);
#pragma unroll
    for (int s = 1; s < RS; ++s) {
        float x = p[(size_t)s * D];
        float ax = fabsf(x);
        if (ax > ba) { ba = ax; best = x; }   // strict > keeps first (argmax)
    }
    rv[i] = best;
}

__global__ void assemble(const float* __restrict__ h, const float* __restrict__ rv,
                         const float* __restrict__ cls, const float* __restrict__ ringt,
                         const float* __restrict__ endt, float* __restrict__ seq) {
    int i = blockIdx.x * 256 + threadIdx.x;
    if (i >= NSEQ * D) return;
    int row = i >> 9, d = i & 511;
    int b = row / SEQS, p = row % SEQS;
    float val;
    if (p == 0)        val = cls[d];
    else if (p <= 128) val = h[((size_t)b * 128 + (p - 1)) * D + d];
    else if (p == 129) val = ringt[d];
    else if (p <= 137) val = rv[((size_t)b * 8 + (p - 130)) * D + d];
    else               val = endt[d];
    seq[i] = val;
}

// ---------------------------------------------------------------------------
extern "C" void kernel_launch(void* const* d_in, const int* in_sizes, int n_in,
                              void* d_out, int out_size, void* d_ws, size_t ws_size,
                              hipStream_t stream) {
    (void)in_sizes; (void)n_in; (void)out_size; (void)ws_size;

    const float* x          = (const float*)d_in[0];
    const float* edge_attr  = (const float*)d_in[1];
    const int*   ei         = (const int*)  d_in[2];
    const int*   rings_idx  = (const int*)  d_in[3];
    const float* x_proj_w   = (const float*)d_in[8];
    const float* x_proj_b   = (const float*)d_in[9];
    const float* e_proj_w   = (const float*)d_in[10];
    const float* e_proj_b   = (const float*)d_in[11];
    const float* gat_wl     = (const float*)d_in[12];
    const float* gat_bl     = (const float*)d_in[13];
    const float* gat_wr     = (const float*)d_in[14];
    const float* gat_br     = (const float*)d_in[15];
    const float* gat_we     = (const float*)d_in[16];
    const float* gat_att    = (const float*)d_in[17];
    const float* gat_bias   = (const float*)d_in[18];
    const float* gat_ln     = (const float*)d_in[19];
    const float* ring_attn_w= (const float*)d_in[20];
    const float* ring_attn_b= (const float*)d_in[21];
    const float* ring_w1    = (const float*)d_in[22];
    const float* ring_b1    = (const float*)d_in[23];
    const float* ring_w2    = (const float*)d_in[24];
    const float* ring_b2    = (const float*)d_in[25];
    const float* ring_ln    = (const float*)d_in[26];
    const float* mol_attn_w = (const float*)d_in[27];
    const float* mol_attn_b = (const float*)d_in[28];
    const float* mol_w1     = (const float*)d_in[29];
    const float* mol_b1     = (const float*)d_in[30];
    const float* mol_w2     = (const float*)d_in[31];
    const float* mol_b2     = (const float*)d_in[32];
    const float* mol_ln     = (const float*)d_in[33];
    const float* cls_tok    = (const float*)d_in[34];
    const float* ring_tok   = (const float*)d_in[35];
    const float* end_tok    = (const float*)d_in[36];

    constexpr size_t MB = 1024 * 1024;
    char* wsb = (char*)d_ws;
#define WSF(off) ((float*)(wsb + (size_t)(off)))

    float* H    = WSF(0);          // [8192,512] node states (persists)
    float* HN   = WSF(16 * MB);    // [8192,512] GAT layer out
    float* XL   = WSF(32 * MB);
    float* XR   = WSF(48 * MB);
    float* EALL = WSF(64 * MB);    // [40960,512]
    float* EWE  = WSF(144 * MB);   // [40960,512]
    float* DEG    = WSF(224 * MB);
    float* SEGMAX = WSF(224 * MB + 32 * 1024);
    float* SEGSUM = WSF(224 * MB + 64 * 1024);
    float* SCORE  = WSF(224 * MB + 96 * 1024);
    float* EXPV   = WSF(224 * MB + 256 * 1024);
    float* RVEC   = WSF(225 * MB);  // [512,512] ring vectors (persists)

    // ring phase (reuses GAT buffers; H persists)
    float* T    = HN;
    float* RQ   = XL;
    float* RK   = XR;
    float* RV   = WSF(64 * MB);
    float* RO   = WSF(64 * MB + 8 * MB);
    float* RTMP = WSF(64 * MB + 16 * MB);
    float* RY   = WSF(64 * MB + 24 * MB);
    float* RFF  = WSF(64 * MB + 32 * MB);   // [3072,2048] 24MB
    float* RT2  = WSF(64 * MB + 56 * MB);

    // mol phase
    float* SEQ  = WSF(16 * MB);   // [8896,512] 17.4MB
    float* MQ   = WSF(34 * MB);
    float* MK   = WSF(52 * MB);
    float* MV   = WSF(70 * MB);
    float* MO   = WSF(88 * MB);
    float* MTMP = MQ;             // after attn, MQ dead
    float* MY   = MK;             // after attn, MK dead
    float* MFF  = MV;             // [8896,2048] 69.5MB over MV/MO/beyond
    float* MT2  = MQ;             // after MY, MTMP dead

    dim3 blk(256);
    auto gemm = [&](const float* A, const float* B, const float* bias, float* C,
                    int M, int Nc, int K, int flags) {
        gemm_f32<<<dim3(M / 64, Nc / 64), blk, 0, stream>>>(A, B, bias, C, M, Nc, K, flags);
    };

    // ---- phase 1: projections + self-loop edges ----
    gemm(x, x_proj_w, x_proj_b, H, NN, D, 64, 1);
    gemm(edge_attr, e_proj_w, e_proj_b, EALL, EE, D, 16, 1);
    hipMemsetAsync(EALL + (size_t)EE * D, 0, (size_t)NN * D * 4, stream);
    hipMemsetAsync(DEG, 0, NN * 4, stream);
    deg_count<<<EE / 256, blk, 0, stream>>>(ei, DEG);
    loop_acc<<<EE / 4, blk, 0, stream>>>(EALL, ei, EALL + (size_t)EE * D);
    loop_scale<<<NN / 4, blk, 0, stream>>>(EALL + (size_t)EE * D, DEG);

    // ---- phase 2: 6x GATv2 ----
    for (int l = 0; l < 6; ++l) {
        const float* wl = gat_wl + (size_t)l * D * D;
        const float* wr = gat_wr + (size_t)l * D * D;
        const float* we = gat_we + (size_t)l * D * D;
        gemm(H, wl, gat_bl + l * D, XL, NN, D, D, 1);
        gemm(H, wr, gat_br + l * D, XR, NN, D, D, 1);
        gemm(EALL, we, nullptr, EWE, ENL, D, D, 0);
        gat_score<<<ENL / 4, blk, 0, stream>>>(XL, XR, EWE, ei, gat_att + l * D, SCORE);
        fill_f32<<<NN / 256, blk, 0, stream>>>(SEGMAX, -1e30f, NN);
        hipMemsetAsync(SEGSUM, 0, NN * 4, stream);
        seg_max_k<<<ENL / 256, blk, 0, stream>>>(SCORE, ei, SEGMAX);
        seg_exp_k<<<ENL / 256, blk, 0, stream>>>(SCORE, ei, SEGMAX, EXPV, SEGSUM);
        hipMemsetAsync(HN, 0, (size_t)NN * D * 4, stream);
        gat_scatter<<<ENL / 4, blk, 0, stream>>>(XL, ei, EXPV, SEGSUM, HN);
        if (l < 5) {
            ln_rows<<<NN / 4, blk, 0, stream>>>(HN, nullptr, gat_bias + l * D,
                gat_ln + (size_t)l * 2 * D, gat_ln + (size_t)l * 2 * D + D, H, NN, 3);
        } else {
            ln_rows<<<NN / 4, blk, 0, stream>>>(HN, nullptr, gat_bias + l * D,
                nullptr, nullptr, H, NN, 0);
        }
    }

    // ---- phase 3: ring encoder ----
    const int RROWS = RGS * RS;  // 3072
    gather_rows<<<RROWS * D / 256, blk, 0, stream>>>(H, rings_idx, T, RROWS);
    gemm(T, ring_attn_w + 0 * D * D, ring_attn_b + 0 * D, RQ, RROWS, D, D, 1);
    gemm(T, ring_attn_w + 1 * D * D, ring_attn_b + 1 * D, RK, RROWS, D, D, 1);
    gemm(T, ring_attn_w + 2 * D * D, ring_attn_b + 2 * D, RV, RROWS, D, D, 1);
    ring_attn<<<RGS * 2, blk, 0, stream>>>(RQ, RK, RV, RO);
    gemm(RO, ring_attn_w + 3 * D * D, ring_attn_b + 3 * D, RTMP, RROWS, D, D, 1);
    ln_rows<<<RROWS / 4, blk, 0, stream>>>(RTMP, T, nullptr, ring_ln, ring_ln + D, RY, RROWS, 2);
    gemm(RY, ring_w1, ring_b1, RFF, RROWS, DFF, D, 3);
    gemm(RFF, ring_w2, ring_b2, RTMP, RROWS, D, DFF, 1);
    ln_rows<<<RROWS / 4, blk, 0, stream>>>(RTMP, RY, nullptr, ring_ln + 2 * D, ring_ln + 3 * D, RT2, RROWS, 2);
    ring_pick<<<RGS * D / 256, blk, 0, stream>>>(RT2, RVEC);

    // ---- phase 4: mol encoder ----
    assemble<<<NSEQ * D / 256, blk, 0, stream>>>(H, RVEC, cls_tok, ring_tok, end_tok, SEQ);
    gemm(SEQ, mol_attn_w + 0 * D * D, mol_attn_b + 0 * D, MQ, NSEQ, D, D, 1);
    gemm(SEQ, mol_attn_w + 1 * D * D, mol_attn_b + 1 * D, MK, NSEQ, D, D, 1);
    gemm(SEQ, mol_attn_w + 2 * D * D, mol_attn_b + 2 * D, MV, NSEQ, D, D, 1);
    mol_attn<<<BMOL * 4, blk, 0, stream>>>(MQ, MK, MV, MO);
    gemm(MO, mol_attn_w + 3 * D * D, mol_attn_b + 3 * D, MTMP, NSEQ, D, D, 1);
    ln_rows<<<NSEQ / 4, blk, 0, stream>>>(MTMP, SEQ, nullptr, mol_ln, mol_ln + D, MY, NSEQ, 2);
    gemm(MY, mol_w1, mol_b1, MFF, NSEQ, DFF, D, 3);
    gemm(MFF, mol_w2, mol_b2, MT2, NSEQ, D, DFF, 1);

    float* outf = (float*)d_out;
    ln_rows<<<NSEQ / 4, blk, 0, stream>>>(MT2, MY, nullptr, mol_ln + 2 * D, mol_ln + 3 * D, outf, NSEQ, 2);
    // not_padded_X [64,128] and not_padded_Xr [64,8] -> all ones
    fill_f32<<<(BMOL * 128 + BMOL * 8 + 255) / 256, blk, 0, stream>>>(
        outf + (size_t)NSEQ * D, 1.0f, BMOL * 128 + BMOL * 8);
}

// Round 3
// 4376.685 us; speedup vs baseline: 1.5085x; 1.5085x over previous
//
#include <hip/hip_runtime.h>
#include <math.h>

// ---------------------------------------------------------------------------
// Molecular GNN forward, f32. Round 2 (resubmit after broker timeout):
//  - rank-17 edge-GEMM factorization (EWE eliminated; fused into node kernel)
//  - CSR node-centric GAT (no atomics, 1 kernel per layer + LN)
//  - 128x128-tile f32 GEMM (8x8/thread)
//  - wave-per-query mol attention
// ---------------------------------------------------------------------------

#define DEV __device__ __forceinline__

constexpr int NN   = 8192;
constexpr int EE   = 32768;
constexpr int ENL  = EE + NN;
constexpr int D    = 512;
constexpr int RGS  = 512;
constexpr int RS   = 6;
constexpr int BMOL = 64;
constexpr int SEQS = 139;
constexpr int NSEQ = BMOL * SEQS;  // 8896
constexpr int DFF  = 2048;

DEV float wsum(float v) {
    for (int o = 32; o > 0; o >>= 1) v += __shfl_xor(v, o, 64);
    return v;
}
DEV float wmax(float v) {
    for (int o = 32; o > 0; o >>= 1) v = fmaxf(v, __shfl_xor(v, o, 64));
    return v;
}

// ---------------------------------------------------------------------------
// f32 GEMM: C[M,N] = A[M,K] @ B[K,N] (+bias)(+relu). 128x128 tile, 256 thr,
// 8x8 per thread. N%128==0, K%16==0; M arbitrary (row-guarded).
// flags: 1 = bias, 2 = relu
// ---------------------------------------------------------------------------
__global__ __launch_bounds__(256) void gemm128(
    const float* __restrict__ A, const float* __restrict__ B,
    const float* __restrict__ bias, float* __restrict__ C,
    int M, int N, int K, int flags)
{
    __shared__ float As[16][132];   // k-major, padded: 2-way banks max
    __shared__ float Bs[16][128];
    const int tid = threadIdx.x;
    const int wv = tid >> 6, ln = tid & 63;
    // within-wave: 8 distinct mg and 8 distinct ng -> 2-way LDS access (free)
    const int mg = ((ln >> 3) & 7) | ((wv & 1) << 3);   // 0..15
    const int ng = (ln & 7) | ((wv >> 1) << 3);         // 0..15
    const int m0 = blockIdx.x * 128, n0 = blockIdx.y * 128;

    const int a_row = tid >> 2;   // 0..63 (+64)
    const int a_kg  = tid & 3;    // k group of 4
    const int b_row = tid >> 5;   // 0..7 (+8)
    const int b_cg  = tid & 31;   // col group of 4

    float acc[8][8] = {};
    for (int k0 = 0; k0 < K; k0 += 16) {
#pragma unroll
        for (int i = 0; i < 2; ++i) {
            int r = a_row + i * 64;
            int gr = m0 + r; if (gr >= M) gr = M - 1;
            float4 av = *(const float4*)&A[(size_t)gr * K + k0 + a_kg * 4];
            As[a_kg * 4 + 0][r] = av.x;
            As[a_kg * 4 + 1][r] = av.y;
            As[a_kg * 4 + 2][r] = av.z;
            As[a_kg * 4 + 3][r] = av.w;
        }
#pragma unroll
        for (int i = 0; i < 2; ++i) {
            int r = b_row + i * 8;
            float4 bv = *(const float4*)&B[(size_t)(k0 + r) * N + n0 + b_cg * 4];
            *(float4*)&Bs[r][b_cg * 4] = bv;
        }
        __syncthreads();
#pragma unroll
        for (int k = 0; k < 16; ++k) {
            float a0[8], b0[8];
            *(float4*)&a0[0] = *(const float4*)&As[k][mg * 8];
            *(float4*)&a0[4] = *(const float4*)&As[k][mg * 8 + 4];
            *(float4*)&b0[0] = *(const float4*)&Bs[k][ng * 8];
            *(float4*)&b0[4] = *(const float4*)&Bs[k][ng * 8 + 4];
#pragma unroll
            for (int i = 0; i < 8; ++i)
#pragma unroll
                for (int j = 0; j < 8; ++j) acc[i][j] += a0[i] * b0[j];
        }
        __syncthreads();
    }
#pragma unroll
    for (int i = 0; i < 8; ++i) {
        int gr = m0 + mg * 8 + i;
        if (gr >= M) break;
        float* cp = &C[(size_t)gr * N + n0 + ng * 8];
        float o[8];
#pragma unroll
        for (int j = 0; j < 8; ++j) o[j] = acc[i][j];
        if (flags & 1) {
            const float* bp = bias + n0 + ng * 8;
#pragma unroll
            for (int j = 0; j < 8; ++j) o[j] += bp[j];
        }
        if (flags & 2) {
#pragma unroll
            for (int j = 0; j < 8; ++j) o[j] = fmaxf(o[j], 0.f);
        }
        *(float4*)&cp[0] = make_float4(o[0], o[1], o[2], o[3]);
        *(float4*)&cp[4] = make_float4(o[4], o[5], o[6], o[7]);
    }
}

// ---------------------------------------------------------------------------
// Row LayerNorm (D=512), wave per row. flags: 1 = relu, 2 = LN (0: x+bias)
// ---------------------------------------------------------------------------
__global__ __launch_bounds__(256) void ln_rows(
    const float* __restrict__ x, const float* __restrict__ res,
    const float* __restrict__ bias, const float* __restrict__ g,
    const float* __restrict__ be, float* __restrict__ out, int rows, int flags)
{
    int r = blockIdx.x * 4 + (threadIdx.x >> 6);
    if (r >= rows) return;
    int lane = threadIdx.x & 63;
    size_t base = (size_t)r * D;
    float v[8];
#pragma unroll
    for (int i = 0; i < 8; ++i) {
        int d = lane + i * 64;
        float t = x[base + d];
        if (res)  t += res[base + d];
        if (bias) t += bias[d];
        v[i] = t;
    }
    if (flags & 2) {
        float s = 0;
#pragma unroll
        for (int i = 0; i < 8; ++i) s += v[i];
        float mu = wsum(s) * (1.f / 512.f);
        float q = 0;
#pragma unroll
        for (int i = 0; i < 8; ++i) { float d0 = v[i] - mu; q += d0 * d0; }
        float inv = rsqrtf(wsum(q) * (1.f / 512.f) + 1e-5f);
#pragma unroll
        for (int i = 0; i < 8; ++i) {
            int d = lane + i * 64;
            float o = (v[i] - mu) * inv * g[d] + be[d];
            if (flags & 1) o = fmaxf(o, 0.f);
            out[base + d] = o;
        }
    } else {
#pragma unroll
        for (int i = 0; i < 8; ++i) {
            int d = lane + i * 64;
            float o = v[i];
            if (flags & 1) o = fmaxf(o, 0.f);
            out[base + d] = o;
        }
    }
}

__global__ void fill_f32(float* p, float v, int n) {
    int i = blockIdx.x * 256 + threadIdx.x;
    if (i < n) p[i] = v;
}

// ---------------------------------------------------------------------------
// Graph preprocessing (per call; cheap)
// ---------------------------------------------------------------------------
__global__ void deg_int(const int* __restrict__ ei, int* __restrict__ degi) {
    int e = blockIdx.x * 256 + threadIdx.x;
    if (e >= EE) return;
    atomicAdd(&degi[ei[EE + e]], 1);
}

// exclusive scan of degi[8192] -> off[8193]; single block, 256 threads
__global__ __launch_bounds__(256) void scan_deg(const int* __restrict__ degi,
                                                int* __restrict__ off) {
    __shared__ int ps[256];
    int tid = threadIdx.x;
    int base = tid * 32;
    int loc[32];
    int s = 0;
#pragma unroll
    for (int i = 0; i < 32; ++i) { loc[i] = s; s += degi[base + i]; }
    ps[tid] = s;
    __syncthreads();
    for (int o = 1; o < 256; o <<= 1) {
        int v = (tid >= o) ? ps[tid - o] : 0;
        __syncthreads();
        ps[tid] += v;
        __syncthreads();
    }
    int pre = (tid == 0) ? 0 : ps[tid - 1];
#pragma unroll
    for (int i = 0; i < 32; ++i) off[base + i] = pre + loc[i];
    if (tid == 255) off[8192] = ps[255];
}

__global__ void csr_fill(const int* __restrict__ ei, int* __restrict__ cnt,
                         const int* __restrict__ off, int* __restrict__ adj) {
    int e = blockIdx.x * 256 + threadIdx.x;
    if (e >= EE) return;
    int dn = ei[EE + e];
    int p = atomicAdd(&cnt[dn], 1);
    adj[off[dn] + p] = e;
}

__global__ void eagg_acc(const float* __restrict__ eattr, const int* __restrict__ ei,
                         float* __restrict__ agg) {
    int id = blockIdx.x * 256 + threadIdx.x;
    if (id >= EE * 16) return;
    int e = id >> 4, c = id & 15;
    atomicAdd(&agg[(size_t)ei[EE + e] * 16 + c], eattr[id]);
}

// EIN17[ENL][17]: edges: [edge_attr row, 1]; loops: [agg/max(deg,1), deg>0]
__global__ void ein_build(const float* __restrict__ eattr, const float* __restrict__ agg,
                          const int* __restrict__ degi, float* __restrict__ ein) {
    int r = blockIdx.x * 256 + threadIdx.x;
    if (r >= ENL) return;
    float* o = &ein[(size_t)r * 17];
    if (r < EE) {
        const float* a = &eattr[(size_t)r * 16];
#pragma unroll
        for (int k = 0; k < 16; ++k) o[k] = a[k];
        o[16] = 1.f;
    } else {
        int n = r - EE;
        int dg = degi[n];
        float inv = 1.f / (float)(dg > 1 ? dg : 1);
        const float* a = &agg[(size_t)n * 16];
#pragma unroll
        for (int k = 0; k < 16; ++k) o[k] = a[k] * inv;
        o[16] = dg > 0 ? 1.f : 0.f;
    }
}

// WE17[17][512] = [e_proj_w(16x512); e_proj_b] @ we(512x512)
__global__ __launch_bounds__(256) void we17_build(
    const float* __restrict__ epw, const float* __restrict__ epb,
    const float* __restrict__ we, float* __restrict__ we17) {
    int j = blockIdx.x * 256 + threadIdx.x;   // 0..511
    float acc[17];
#pragma unroll
    for (int i = 0; i < 17; ++i) acc[i] = 0.f;
    for (int k = 0; k < 512; ++k) {
        float wkj = we[(size_t)k * 512 + j];
#pragma unroll
        for (int i = 0; i < 16; ++i) acc[i] += epw[(size_t)i * 512 + k] * wkj;
        acc[16] += epb[k] * wkj;
    }
#pragma unroll
    for (int i = 0; i < 17; ++i) we17[(size_t)i * 512 + j] = acc[i];
}

// ---------------------------------------------------------------------------
// GATv2 per-node: scores (with fused rank-17 ewe), softmax, aggregate.
// wave per node; 4 waves/block. No atomics.
// ---------------------------------------------------------------------------
__global__ __launch_bounds__(256) void gat_node(
    const float* __restrict__ xl, const float* __restrict__ xr,
    const float* __restrict__ ein, const float* __restrict__ we17,
    const int* __restrict__ off, const int* __restrict__ adj,
    const int* __restrict__ ei, const float* __restrict__ att,
    float* __restrict__ out)
{
    __shared__ float we[17][512];
    __shared__ float sc[4][88];
    int tid = threadIdx.x;
    for (int i = tid; i < 17 * 512; i += 256) we[i >> 9][i & 511] = we17[i];
    __syncthreads();
    int wv = tid >> 6, lane = tid & 63;
    int n = blockIdx.x * 4 + wv;
    float xr8[8], att8[8];
#pragma unroll
    for (int i = 0; i < 8; ++i) {
        int d = lane + i * 64;
        xr8[i] = xr[(size_t)n * D + d];
        att8[i] = att[d];
    }
    int o0 = off[n];
    int deg = off[n + 1] - o0;
    if (deg > 80) deg = 80;   // structurally impossible for this graph
    for (int j = 0; j <= deg; ++j) {        // j==deg: self-loop
        int er, s;
        if (j < deg) { int e = adj[o0 + j]; er = e; s = ei[e]; }
        else         { er = EE + n; s = n; }
        const float* ep = &ein[(size_t)er * 17];
        float e17[17];
#pragma unroll
        for (int k = 0; k < 17; ++k) e17[k] = ep[k];
        float a = 0;
#pragma unroll
        for (int i = 0; i < 8; ++i) {
            int d = lane + i * 64;
            float m = xl[(size_t)s * D + d] + xr8[i];
#pragma unroll
            for (int k = 0; k < 17; ++k) m += e17[k] * we[k][d];
            m = m > 0.f ? m : 0.2f * m;
            a += att8[i] * m;
        }
        a = wsum(a);
        if (lane == 0) sc[wv][j] = a;
    }
    __syncthreads();
    float mx = -1e30f;
    for (int j = 0; j <= deg; ++j) mx = fmaxf(mx, sc[wv][j]);
    float z = 0;
    for (int j = 0; j <= deg; ++j) z += expf(sc[wv][j] - mx);
    float acc[8] = {};
    for (int j = 0; j <= deg; ++j) {
        int s = (j < deg) ? ei[adj[o0 + j]] : n;
        float w = expf(sc[wv][j] - mx);
#pragma unroll
        for (int i = 0; i < 8; ++i) acc[i] += w * xl[(size_t)s * D + lane + i * 64];
    }
    float inv = 1.f / z;
#pragma unroll
    for (int i = 0; i < 8; ++i) out[(size_t)n * D + lane + i * 64] = acc[i] * inv;
}

// ---------------------------------------------------------------------------
// Ring / mol helpers
// ---------------------------------------------------------------------------
__global__ void gather_rows(const float* __restrict__ src, const int* __restrict__ idx,
                            float* __restrict__ dst, int nrows) {
    int i = blockIdx.x * 256 + threadIdx.x;
    int r = i >> 9;
    if (r >= nrows) return;
    dst[i] = src[(size_t)idx[r] * D + (i & 511)];
}

// ring attention: nh=2, dh=256, S=6; block per (ring, head)
__global__ __launch_bounds__(256) void ring_attn(
    const float* __restrict__ q, const float* __restrict__ k,
    const float* __restrict__ v, float* __restrict__ o)
{
    int rh = blockIdx.x, r = rh >> 1, hh = rh & 1;
    __shared__ float qs[RS * 256], ks[RS * 256], vs[RS * 256];
    __shared__ float scs[36], pr[36];
    int tid = threadIdx.x;
    size_t base = (size_t)r * RS * D + hh * 256;
    for (int i = tid; i < RS * 256; i += 256) {
        int si = i >> 8, d = i & 255;
        size_t g = base + (size_t)si * D + d;
        qs[i] = q[g]; ks[i] = k[g]; vs[i] = v[g];
    }
    __syncthreads();
    if (tid < 36) {
        int i = tid / 6, j = tid % 6;
        float a = 0;
        for (int d = 0; d < 256; ++d) a += qs[i * 256 + d] * ks[j * 256 + d];
        scs[tid] = a * (1.f / 16.f);
    }
    __syncthreads();
    if (tid < 6) {
        float mx = -1e30f;
        for (int j = 0; j < 6; ++j) mx = fmaxf(mx, scs[tid * 6 + j]);
        float p[6], s = 0;
        for (int j = 0; j < 6; ++j) { p[j] = expf(scs[tid * 6 + j] - mx); s += p[j]; }
        for (int j = 0; j < 6; ++j) pr[tid * 6 + j] = p[j] / s;
    }
    __syncthreads();
    for (int i = tid; i < RS * 256; i += 256) {
        int si = i >> 8, d = i & 255;
        float a = 0;
        for (int j = 0; j < 6; ++j) a += pr[si * 6 + j] * vs[j * 256 + d];
        o[base + (size_t)si * D + d] = a;
    }
}

// mol attention: nh=4, dh=128, S=139; wave per query. grid (B*4, ceil(139/4))
__global__ __launch_bounds__(256) void mol_attn2(
    const float* __restrict__ q, const float* __restrict__ k,
    const float* __restrict__ v, float* __restrict__ o)
{
    __shared__ float qs[4][128];
    __shared__ float ps[4][140];
    int bh = blockIdx.x;
    int b = bh >> 2, hh = bh & 3;
    int wv = threadIdx.x >> 6, lane = threadIdx.x & 63;
    int qi = blockIdx.y * 4 + wv;
    bool act = qi < SEQS;
    size_t hb = (size_t)b * SEQS * D + hh * 128;
    if (act) {
        qs[wv][lane]      = q[hb + (size_t)qi * D + lane];
        qs[wv][lane + 64] = q[hb + (size_t)qi * D + lane + 64];
    }
    __syncthreads();
    float s[3] = {-1e30f, -1e30f, -1e30f};
    if (act) {
#pragma unroll
        for (int jj = 0; jj < 3; ++jj) {
            int j = lane + jj * 64;
            if (j < SEQS) {
                const float* kp = &k[hb + (size_t)j * D];
                float a = 0;
#pragma unroll 8
                for (int d4 = 0; d4 < 32; ++d4) {
                    float4 kv = *(const float4*)&kp[d4 * 4];
                    float4 qv = *(const float4*)&qs[wv][d4 * 4];
                    a += qv.x * kv.x + qv.y * kv.y + qv.z * kv.z + qv.w * kv.w;
                }
                s[jj] = a * 0.08838834764831845f;
            }
        }
    }
    float mx = wmax(fmaxf(fmaxf(s[0], s[1]), s[2]));
    float lsum = 0;
#pragma unroll
    for (int jj = 0; jj < 3; ++jj) {
        int j = lane + jj * 64;
        if (act && j < SEQS) {
            float p = expf(s[jj] - mx);
            ps[wv][j] = p;
            lsum += p;
        }
    }
    float z = wsum(lsum);
    __syncthreads();
    if (act) {
        float a0 = 0, a1 = 0;
        for (int j = 0; j < SEQS; ++j) {
            float p = ps[wv][j];
            const float* vp = &v[hb + (size_t)j * D];
            a0 += p * vp[lane];
            a1 += p * vp[lane + 64];
        }
        float inv = 1.f / z;
        o[hb + (size_t)qi * D + lane]      = a0 * inv;
        o[hb + (size_t)qi * D + lane + 64] = a1 * inv;
    }
}

// per (ring, channel) abs-argmax gather over S=6
__global__ void ring_pick(const float* __restrict__ t, float* __restrict__ rv) {
    int i = blockIdx.x * 256 + threadIdx.x;
    if (i >= RGS * D) return;
    int r = i >> 9, d = i & 511;
    const float* p = &t[(size_t)r * RS * D + d];
    float best = p[0], ba = fabsf(best);
#pragma unroll
    for (int s = 1; s < RS; ++s) {
        float x = p[(size_t)s * D];
        float ax = fabsf(x);
        if (ax > ba) { ba = ax; best = x; }
    }
    rv[i] = best;
}

__global__ void assemble(const float* __restrict__ h, const float* __restrict__ rv,
                         const float* __restrict__ cls, const float* __restrict__ ringt,
                         const float* __restrict__ endt, float* __restrict__ seq) {
    int i = blockIdx.x * 256 + threadIdx.x;
    if (i >= NSEQ * D) return;
    int row = i >> 9, d = i & 511;
    int b = row / SEQS, p = row % SEQS;
    float val;
    if (p == 0)        val = cls[d];
    else if (p <= 128) val = h[((size_t)b * 128 + (p - 1)) * D + d];
    else if (p == 129) val = ringt[d];
    else if (p <= 137) val = rv[((size_t)b * 8 + (p - 130)) * D + d];
    else               val = endt[d];
    seq[i] = val;
}

// ---------------------------------------------------------------------------
extern "C" void kernel_launch(void* const* d_in, const int* in_sizes, int n_in,
                              void* d_out, int out_size, void* d_ws, size_t ws_size,
                              hipStream_t stream) {
    (void)in_sizes; (void)n_in; (void)out_size; (void)ws_size;

    const float* x          = (const float*)d_in[0];
    const float* edge_attr  = (const float*)d_in[1];
    const int*   ei         = (const int*)  d_in[2];
    const int*   rings_idx  = (const int*)  d_in[3];
    const float* x_proj_w   = (const float*)d_in[8];
    const float* x_proj_b   = (const float*)d_in[9];
    const float* e_proj_w   = (const float*)d_in[10];
    const float* e_proj_b   = (const float*)d_in[11];
    const float* gat_wl     = (const float*)d_in[12];
    const float* gat_bl     = (const float*)d_in[13];
    const float* gat_wr     = (const float*)d_in[14];
    const float* gat_br     = (const float*)d_in[15];
    const float* gat_we     = (const float*)d_in[16];
    const float* gat_att    = (const float*)d_in[17];
    const float* gat_bias   = (const float*)d_in[18];
    const float* gat_ln     = (const float*)d_in[19];
    const float* ring_attn_w= (const float*)d_in[20];
    const float* ring_attn_b= (const float*)d_in[21];
    const float* ring_w1    = (const float*)d_in[22];
    const float* ring_b1    = (const float*)d_in[23];
    const float* ring_w2    = (const float*)d_in[24];
    const float* ring_b2    = (const float*)d_in[25];
    const float* ring_ln    = (const float*)d_in[26];
    const float* mol_attn_w = (const float*)d_in[27];
    const float* mol_attn_b = (const float*)d_in[28];
    const float* mol_w1     = (const float*)d_in[29];
    const float* mol_b1     = (const float*)d_in[30];
    const float* mol_w2     = (const float*)d_in[31];
    const float* mol_b2     = (const float*)d_in[32];
    const float* mol_ln     = (const float*)d_in[33];
    const float* cls_tok    = (const float*)d_in[34];
    const float* ring_tok   = (const float*)d_in[35];
    const float* end_tok    = (const float*)d_in[36];

    constexpr size_t MB = 1024 * 1024;
    char* wsb = (char*)d_ws;
#define WSF(off) ((float*)(wsb + (size_t)(off)))
#define WSI(off) ((int*)(wsb + (size_t)(off)))

    float* H    = WSF(0);                 // [8192,512] persists
    float* XL   = WSF(16 * MB);
    float* XR   = WSF(32 * MB);
    float* HN   = WSF(48 * MB);
    float* EIN  = WSF(64 * MB);           // [40960,17]  2.79MB
    float* WE17 = WSF(67 * MB);           // [17,512]
    float* AGG  = WSF(68 * MB);           // [8192,16]   512KB
    int*   DEGI = WSI(68 * MB + 512 * 1024);
    int*   OFF  = WSI(68 * MB + 576 * 1024);
    int*   CNT  = WSI(68 * MB + 640 * 1024);
    int*   ADJ  = WSI(68 * MB + 704 * 1024);   // 128KB
    float* RVEC = WSF(70 * MB);           // [512,512] persists into mol phase

    // ring phase
    float* T    = WSF(71 * MB);
    float* RQ   = WSF(77 * MB);
    float* RK   = WSF(83 * MB);
    float* RV   = WSF(89 * MB);
    float* RO   = WSF(95 * MB);
    float* RTMP = WSF(101 * MB);
    float* RY   = WSF(107 * MB);
    float* RFF  = WSF(113 * MB);          // [3072,2048] 24MB
    float* RT2  = WSF(137 * MB);

    // mol phase (ring buffers dead, reuse region)
    float* SEQ  = WSF(71 * MB);           // [8896,512] 17.4MB
    float* MQ   = WSF(89 * MB);
    float* MK   = WSF(107 * MB);
    float* MV   = WSF(125 * MB);
    float* MO   = WSF(143 * MB);
    float* MTMP = WSF(89 * MB);           // = MQ (dead after attn)
    float* MY   = WSF(107 * MB);          // = MK (dead after attn)
    float* MFF  = WSF(125 * MB);          // [8896,2048] 69.6MB over MV/MO + free
    float* MT2  = WSF(89 * MB);           // = MTMP (dead after MY)

    dim3 blk(256);
    auto gemm = [&](const float* A, const float* B, const float* bias, float* C,
                    int M, int Nc, int K, int flags) {
        gemm128<<<dim3((M + 127) / 128, Nc / 128), blk, 0, stream>>>(A, B, bias, C, M, Nc, K, flags);
    };

    // ---- phase 0: graph preprocessing ----
    hipMemsetAsync(DEGI, 0, NN * 4, stream);
    hipMemsetAsync(CNT, 0, NN * 4, stream);
    hipMemsetAsync(AGG, 0, (size_t)NN * 16 * 4, stream);
    deg_int<<<EE / 256, blk, 0, stream>>>(ei, DEGI);
    scan_deg<<<1, blk, 0, stream>>>(DEGI, OFF);
    csr_fill<<<EE / 256, blk, 0, stream>>>(ei, CNT, OFF, ADJ);
    eagg_acc<<<EE * 16 / 256, blk, 0, stream>>>(edge_attr, ei, AGG);
    ein_build<<<ENL / 256, blk, 0, stream>>>(edge_attr, AGG, DEGI, EIN);

    // ---- phase 1: x projection ----
    gemm(x, x_proj_w, x_proj_b, H, NN, D, 64, 1);

    // ---- phase 2: 6x GATv2 ----
    for (int l = 0; l < 6; ++l) {
        we17_build<<<2, blk, 0, stream>>>(e_proj_w, e_proj_b,
                                          gat_we + (size_t)l * D * D, WE17);
        gemm(H, gat_wl + (size_t)l * D * D, gat_bl + l * D, XL, NN, D, D, 1);
        gemm(H, gat_wr + (size_t)l * D * D, gat_br + l * D, XR, NN, D, D, 1);
        gat_node<<<NN / 4, blk, 0, stream>>>(XL, XR, EIN, WE17, OFF, ADJ, ei,
                                             gat_att + l * D, HN);
        if (l < 5) {
            ln_rows<<<NN / 4, blk, 0, stream>>>(HN, nullptr, gat_bias + l * D,
                gat_ln + (size_t)l * 2 * D, gat_ln + (size_t)l * 2 * D + D, H, NN, 3);
        } else {
            ln_rows<<<NN / 4, blk, 0, stream>>>(HN, nullptr, gat_bias + l * D,
                nullptr, nullptr, H, NN, 0);
        }
    }

    // ---- phase 3: ring encoder ----
    const int RROWS = RGS * RS;  // 3072
    gather_rows<<<RROWS * D / 256, blk, 0, stream>>>(H, rings_idx, T, RROWS);
    gemm(T, ring_attn_w + 0 * D * D, ring_attn_b + 0 * D, RQ, RROWS, D, D, 1);
    gemm(T, ring_attn_w + 1 * D * D, ring_attn_b + 1 * D, RK, RROWS, D, D, 1);
    gemm(T, ring_attn_w + 2 * D * D, ring_attn_b + 2 * D, RV, RROWS, D, D, 1);
    ring_attn<<<RGS * 2, blk, 0, stream>>>(RQ, RK, RV, RO);
    gemm(RO, ring_attn_w + 3 * D * D, ring_attn_b + 3 * D, RTMP, RROWS, D, D, 1);
    ln_rows<<<RROWS / 4, blk, 0, stream>>>(RTMP, T, nullptr, ring_ln, ring_ln + D, RY, RROWS, 2);
    gemm(RY, ring_w1, ring_b1, RFF, RROWS, DFF, D, 3);
    gemm(RFF, ring_w2, ring_b2, RTMP, RROWS, D, DFF, 1);
    ln_rows<<<RROWS / 4, blk, 0, stream>>>(RTMP, RY, nullptr, ring_ln + 2 * D, ring_ln + 3 * D, RT2, RROWS, 2);
    ring_pick<<<RGS * D / 256, blk, 0, stream>>>(RT2, RVEC);

    // ---- phase 4: mol encoder ----
    assemble<<<(NSEQ * D) / 256, blk, 0, stream>>>(H, RVEC, cls_tok, ring_tok, end_tok, SEQ);
    gemm(SEQ, mol_attn_w + 0 * D * D, mol_attn_b + 0 * D, MQ, NSEQ, D, D, 1);
    gemm(SEQ, mol_attn_w + 1 * D * D, mol_attn_b + 1 * D, MK, NSEQ, D, D, 1);
    gemm(SEQ, mol_attn_w + 2 * D * D, mol_attn_b + 2 * D, MV, NSEQ, D, D, 1);
    mol_attn2<<<dim3(BMOL * 4, (SEQS + 3) / 4), blk, 0, stream>>>(MQ, MK, MV, MO);
    gemm(MO, mol_attn_w + 3 * D * D, mol_attn_b + 3 * D, MTMP, NSEQ, D, D, 1);
    ln_rows<<<(NSEQ + 3) / 4, blk, 0, stream>>>(MTMP, SEQ, nullptr, mol_ln, mol_ln + D, MY, NSEQ, 2);
    gemm(MY, mol_w1, mol_b1, MFF, NSEQ, DFF, D, 3);
    gemm(MFF, mol_w2, mol_b2, MT2, NSEQ, D, DFF, 1);

    float* outf = (float*)d_out;
    ln_rows<<<(NSEQ + 3) / 4, blk, 0, stream>>>(MT2, MY, nullptr, mol_ln + 2 * D, mol_ln + 3 * D, outf, NSEQ, 2);
    fill_f32<<<(BMOL * 128 + BMOL * 8 + 255) / 256, blk, 0, stream>>>(
        outf + (size_t)NSEQ * D, 1.0f, BMOL * 128 + BMOL * 8);
}

// Round 4
// 3923.262 us; speedup vs baseline: 1.6828x; 1.1156x over previous
//
#include <hip/hip_runtime.h>
#include <math.h>

// ---------------------------------------------------------------------------
// Round 4: mol-encoder GEMMs -> MFMA bf16x3 split (f32-split hi/lo, 3 products)
// Upstream (GAT + ring, feeds abs-argmax) stays f32 vector GEMM (precision).
// mol_attn2: 8 queries/block (halve K/V re-reads).
// ---------------------------------------------------------------------------

#define DEV __device__ __forceinline__

constexpr int NN   = 8192;
constexpr int EE   = 32768;
constexpr int ENL  = EE + NN;
constexpr int D    = 512;
constexpr int RGS  = 512;
constexpr int RS   = 6;
constexpr int BMOL = 64;
constexpr int SEQS = 139;
constexpr int NSEQ = BMOL * SEQS;  // 8896
constexpr int MHAT = 8960;         // 70 tiles of 128 (padded rows)
constexpr int DFF  = 2048;

typedef short bf8 __attribute__((ext_vector_type(8)));
typedef float f32x4 __attribute__((ext_vector_type(4)));

DEV float wsum(float v) {
    for (int o = 32; o > 0; o >>= 1) v += __shfl_xor(v, o, 64);
    return v;
}
DEV float wmax(float v) {
    for (int o = 32; o > 0; o >>= 1) v = fmaxf(v, __shfl_xor(v, o, 64));
    return v;
}

DEV unsigned short f2bf(float x) {
    unsigned u = __float_as_uint(x);
    u += 0x7FFFu + ((u >> 16) & 1u);
    return (unsigned short)(u >> 16);
}
DEV float bf2f(unsigned short h) { return __uint_as_float((unsigned)h << 16); }

// ---------------------------------------------------------------------------
// f32 GEMM (upstream, unchanged): 128x128 tile, 8x8/thread
// ---------------------------------------------------------------------------
__global__ __launch_bounds__(256) void gemm128(
    const float* __restrict__ A, const float* __restrict__ B,
    const float* __restrict__ bias, float* __restrict__ C,
    int M, int N, int K, int flags)
{
    __shared__ float As[16][132];
    __shared__ float Bs[16][128];
    const int tid = threadIdx.x;
    const int wv = tid >> 6, ln = tid & 63;
    const int mg = ((ln >> 3) & 7) | ((wv & 1) << 3);
    const int ng = (ln & 7) | ((wv >> 1) << 3);
    const int m0 = blockIdx.x * 128, n0 = blockIdx.y * 128;

    const int a_row = tid >> 2;
    const int a_kg  = tid & 3;
    const int b_row = tid >> 5;
    const int b_cg  = tid & 31;

    float acc[8][8] = {};
    for (int k0 = 0; k0 < K; k0 += 16) {
#pragma unroll
        for (int i = 0; i < 2; ++i) {
            int r = a_row + i * 64;
            int gr = m0 + r; if (gr >= M) gr = M - 1;
            float4 av = *(const float4*)&A[(size_t)gr * K + k0 + a_kg * 4];
            As[a_kg * 4 + 0][r] = av.x;
            As[a_kg * 4 + 1][r] = av.y;
            As[a_kg * 4 + 2][r] = av.z;
            As[a_kg * 4 + 3][r] = av.w;
        }
#pragma unroll
        for (int i = 0; i < 2; ++i) {
            int r = b_row + i * 8;
            float4 bv = *(const float4*)&B[(size_t)(k0 + r) * N + n0 + b_cg * 4];
            *(float4*)&Bs[r][b_cg * 4] = bv;
        }
        __syncthreads();
#pragma unroll
        for (int k = 0; k < 16; ++k) {
            float a0[8], b0[8];
            *(float4*)&a0[0] = *(const float4*)&As[k][mg * 8];
            *(float4*)&a0[4] = *(const float4*)&As[k][mg * 8 + 4];
            *(float4*)&b0[0] = *(const float4*)&Bs[k][ng * 8];
            *(float4*)&b0[4] = *(const float4*)&Bs[k][ng * 8 + 4];
#pragma unroll
            for (int i = 0; i < 8; ++i)
#pragma unroll
                for (int j = 0; j < 8; ++j) acc[i][j] += a0[i] * b0[j];
        }
        __syncthreads();
    }
#pragma unroll
    for (int i = 0; i < 8; ++i) {
        int gr = m0 + mg * 8 + i;
        if (gr >= M) break;
        float* cp = &C[(size_t)gr * N + n0 + ng * 8];
        float o[8];
#pragma unroll
        for (int j = 0; j < 8; ++j) o[j] = acc[i][j];
        if (flags & 1) {
            const float* bp = bias + n0 + ng * 8;
#pragma unroll
            for (int j = 0; j < 8; ++j) o[j] += bp[j];
        }
        if (flags & 2) {
#pragma unroll
            for (int j = 0; j < 8; ++j) o[j] = fmaxf(o[j], 0.f);
        }
        *(float4*)&cp[0] = make_float4(o[0], o[1], o[2], o[3]);
        *(float4*)&cp[4] = make_float4(o[4], o[5], o[6], o[7]);
    }
}

// ---------------------------------------------------------------------------
// MFMA bf16x3-split GEMM: C[M,N] = A[M,K]@B[K,N], A as (Ah,Al)[M][K] bf16,
// B as (Bh,Bl)[N][K] bf16 (pre-transposed). M multiple of 128 (padded bufs),
// N%128==0, K%32==0. flags: 1 bias, 2 relu, 4 split-bf16 output (Ch,Cl).
// 128x128 tile, 4 waves, each wave 64x64 via 4x4 frags of 16x16x32.
// ---------------------------------------------------------------------------
__global__ __launch_bounds__(256) void gemm_split3(
    const unsigned short* __restrict__ Ah, const unsigned short* __restrict__ Al,
    const unsigned short* __restrict__ Bh, const unsigned short* __restrict__ Bl,
    const float* __restrict__ bias, float* __restrict__ C,
    unsigned short* __restrict__ Ch, unsigned short* __restrict__ Cl,
    int N, int K, int flags)
{
    __shared__ unsigned short sA[2][128][40];   // [hi/lo][row][k], pad 40 -> 2-way banks
    __shared__ unsigned short sB[2][128][40];
    const int tid = threadIdx.x;
    const int wv = tid >> 6, lane = tid & 63;
    const int m0 = blockIdx.x * 128, n0 = blockIdx.y * 128;
    const int srow = tid >> 2, sc8 = (tid & 3) * 8;
    const int mw = (wv & 1) * 64, nw = (wv >> 1) * 64;
    const int fr = lane & 15, fq = lane >> 4;
    const int ko = fq * 8;

    f32x4 acc[4][4];
    f32x4 zero = {0.f, 0.f, 0.f, 0.f};
#pragma unroll
    for (int i = 0; i < 4; ++i)
#pragma unroll
        for (int j = 0; j < 4; ++j) acc[i][j] = zero;

    for (int k0 = 0; k0 < K; k0 += 32) {
#pragma unroll
        for (int h = 0; h < 2; ++h) {
            int r = srow + h * 64;
            *(bf8*)&sA[0][r][sc8] = *(const bf8*)&Ah[(size_t)(m0 + r) * K + k0 + sc8];
            *(bf8*)&sA[1][r][sc8] = *(const bf8*)&Al[(size_t)(m0 + r) * K + k0 + sc8];
            *(bf8*)&sB[0][r][sc8] = *(const bf8*)&Bh[(size_t)(n0 + r) * K + k0 + sc8];
            *(bf8*)&sB[1][r][sc8] = *(const bf8*)&Bl[(size_t)(n0 + r) * K + k0 + sc8];
        }
        __syncthreads();
        bf8 ah[4], al[4], bh[4], bl[4];
#pragma unroll
        for (int t = 0; t < 4; ++t) {
            ah[t] = *(const bf8*)&sA[0][mw + t * 16 + fr][ko];
            al[t] = *(const bf8*)&sA[1][mw + t * 16 + fr][ko];
            bh[t] = *(const bf8*)&sB[0][nw + t * 16 + fr][ko];
            bl[t] = *(const bf8*)&sB[1][nw + t * 16 + fr][ko];
        }
#pragma unroll
        for (int i = 0; i < 4; ++i)
#pragma unroll
            for (int j = 0; j < 4; ++j) {
                acc[i][j] = __builtin_amdgcn_mfma_f32_16x16x32_bf16(ah[i], bh[j], acc[i][j], 0, 0, 0);
                acc[i][j] = __builtin_amdgcn_mfma_f32_16x16x32_bf16(ah[i], bl[j], acc[i][j], 0, 0, 0);
                acc[i][j] = __builtin_amdgcn_mfma_f32_16x16x32_bf16(al[i], bh[j], acc[i][j], 0, 0, 0);
            }
        __syncthreads();
    }
#pragma unroll
    for (int i = 0; i < 4; ++i)
#pragma unroll
        for (int j = 0; j < 4; ++j) {
            int col = n0 + nw + j * 16 + fr;
#pragma unroll
            for (int r = 0; r < 4; ++r) {
                int row = m0 + mw + i * 16 + fq * 4 + r;
                float o = acc[i][j][r];
                if (flags & 1) o += bias[col];
                if (flags & 2) o = fmaxf(o, 0.f);
                size_t idx = (size_t)row * N + col;
                if (flags & 4) {
                    unsigned short hb_ = f2bf(o);
                    Ch[idx] = hb_;
                    Cl[idx] = f2bf(o - bf2f(hb_));
                } else {
                    C[idx] = o;
                }
            }
        }
}

// activation split: f32 -> (hi,lo) bf16, row-major, via float4
__global__ void asplit4(const float* __restrict__ src, unsigned short* __restrict__ hh,
                        unsigned short* __restrict__ ll, int n4) {
    int i = blockIdx.x * 256 + threadIdx.x;
    if (i >= n4) return;
    float4 v = ((const float4*)src)[i];
    ushort4 h, l;
    h.x = f2bf(v.x); l.x = f2bf(v.x - bf2f(h.x));
    h.y = f2bf(v.y); l.y = f2bf(v.y - bf2f(h.y));
    h.z = f2bf(v.z); l.z = f2bf(v.z - bf2f(h.z));
    h.w = f2bf(v.w); l.w = f2bf(v.w - bf2f(h.w));
    ((ushort4*)hh)[i] = h;
    ((ushort4*)ll)[i] = l;
}

// weight split + transpose: W[K][N] f32 -> (Bh,Bl)[N][K] bf16
__global__ void wsplitT(const float* __restrict__ w, unsigned short* __restrict__ bh,
                        unsigned short* __restrict__ bl, int K, int N) {
    int i = blockIdx.x * 256 + threadIdx.x;
    if (i >= K * N) return;
    int k = i / N, n = i - k * N;
    float x = w[i];
    unsigned short h = f2bf(x);
    unsigned short l = f2bf(x - bf2f(h));
    bh[(size_t)n * K + k] = h;
    bl[(size_t)n * K + k] = l;
}

// ---------------------------------------------------------------------------
// Row LayerNorm (D=512), wave per row. flags: 1 = relu, 2 = LN (0: x+bias)
// ---------------------------------------------------------------------------
__global__ __launch_bounds__(256) void ln_rows(
    const float* __restrict__ x, const float* __restrict__ res,
    const float* __restrict__ bias, const float* __restrict__ g,
    const float* __restrict__ be, float* __restrict__ out, int rows, int flags)
{
    int r = blockIdx.x * 4 + (threadIdx.x >> 6);
    if (r >= rows) return;
    int lane = threadIdx.x & 63;
    size_t base = (size_t)r * D;
    float v[8];
#pragma unroll
    for (int i = 0; i < 8; ++i) {
        int d = lane + i * 64;
        float t = x[base + d];
        if (res)  t += res[base + d];
        if (bias) t += bias[d];
        v[i] = t;
    }
    if (flags & 2) {
        float s = 0;
#pragma unroll
        for (int i = 0; i < 8; ++i) s += v[i];
        float mu = wsum(s) * (1.f / 512.f);
        float q = 0;
#pragma unroll
        for (int i = 0; i < 8; ++i) { float d0 = v[i] - mu; q += d0 * d0; }
        float inv = rsqrtf(wsum(q) * (1.f / 512.f) + 1e-5f);
#pragma unroll
        for (int i = 0; i < 8; ++i) {
            int d = lane + i * 64;
            float o = (v[i] - mu) * inv * g[d] + be[d];
            if (flags & 1) o = fmaxf(o, 0.f);
            out[base + d] = o;
        }
    } else {
#pragma unroll
        for (int i = 0; i < 8; ++i) {
            int d = lane + i * 64;
            float o = v[i];
            if (flags & 1) o = fmaxf(o, 0.f);
            out[base + d] = o;
        }
    }
}

__global__ void fill_f32(float* p, float v, int n) {
    int i = blockIdx.x * 256 + threadIdx.x;
    if (i < n) p[i] = v;
}

// ---------------------------------------------------------------------------
// Graph preprocessing
// ---------------------------------------------------------------------------
__global__ void deg_int(const int* __restrict__ ei, int* __restrict__ degi) {
    int e = blockIdx.x * 256 + threadIdx.x;
    if (e >= EE) return;
    atomicAdd(&degi[ei[EE + e]], 1);
}

__global__ __launch_bounds__(256) void scan_deg(const int* __restrict__ degi,
                                                int* __restrict__ off) {
    __shared__ int ps[256];
    int tid = threadIdx.x;
    int base = tid * 32;
    int loc[32];
    int s = 0;
#pragma unroll
    for (int i = 0; i < 32; ++i) { loc[i] = s; s += degi[base + i]; }
    ps[tid] = s;
    __syncthreads();
    for (int o = 1; o < 256; o <<= 1) {
        int v = (tid >= o) ? ps[tid - o] : 0;
        __syncthreads();
        ps[tid] += v;
        __syncthreads();
    }
    int pre = (tid == 0) ? 0 : ps[tid - 1];
#pragma unroll
    for (int i = 0; i < 32; ++i) off[base + i] = pre + loc[i];
    if (tid == 255) off[8192] = ps[255];
}

__global__ void csr_fill(const int* __restrict__ ei, int* __restrict__ cnt,
                         const int* __restrict__ off, int* __restrict__ adj) {
    int e = blockIdx.x * 256 + threadIdx.x;
    if (e >= EE) return;
    int dn = ei[EE + e];
    int p = atomicAdd(&cnt[dn], 1);
    adj[off[dn] + p] = e;
}

__global__ void eagg_acc(const float* __restrict__ eattr, const int* __restrict__ ei,
                         float* __restrict__ agg) {
    int id = blockIdx.x * 256 + threadIdx.x;
    if (id >= EE * 16) return;
    int e = id >> 4, c = id & 15;
    atomicAdd(&agg[(size_t)ei[EE + e] * 16 + c], eattr[id]);
}

__global__ void ein_build(const float* __restrict__ eattr, const float* __restrict__ agg,
                          const int* __restrict__ degi, float* __restrict__ ein) {
    int r = blockIdx.x * 256 + threadIdx.x;
    if (r >= ENL) return;
    float* o = &ein[(size_t)r * 17];
    if (r < EE) {
        const float* a = &eattr[(size_t)r * 16];
#pragma unroll
        for (int k = 0; k < 16; ++k) o[k] = a[k];
        o[16] = 1.f;
    } else {
        int n = r - EE;
        int dg = degi[n];
        float inv = 1.f / (float)(dg > 1 ? dg : 1);
        const float* a = &agg[(size_t)n * 16];
#pragma unroll
        for (int k = 0; k < 16; ++k) o[k] = a[k] * inv;
        o[16] = dg > 0 ? 1.f : 0.f;
    }
}

__global__ __launch_bounds__(256) void we17_build(
    const float* __restrict__ epw, const float* __restrict__ epb,
    const float* __restrict__ we, float* __restrict__ we17) {
    int j = blockIdx.x * 256 + threadIdx.x;
    float acc[17];
#pragma unroll
    for (int i = 0; i < 17; ++i) acc[i] = 0.f;
    for (int k = 0; k < 512; ++k) {
        float wkj = we[(size_t)k * 512 + j];
#pragma unroll
        for (int i = 0; i < 16; ++i) acc[i] += epw[(size_t)i * 512 + k] * wkj;
        acc[16] += epb[k] * wkj;
    }
#pragma unroll
    for (int i = 0; i < 17; ++i) we17[(size_t)i * 512 + j] = acc[i];
}

// ---------------------------------------------------------------------------
// GATv2 per-node (unchanged)
// ---------------------------------------------------------------------------
__global__ __launch_bounds__(256) void gat_node(
    const float* __restrict__ xl, const float* __restrict__ xr,
    const float* __restrict__ ein, const float* __restrict__ we17,
    const int* __restrict__ off, const int* __restrict__ adj,
    const int* __restrict__ ei, const float* __restrict__ att,
    float* __restrict__ out)
{
    __shared__ float we[17][512];
    __shared__ float sc[4][88];
    int tid = threadIdx.x;
    for (int i = tid; i < 17 * 512; i += 256) we[i >> 9][i & 511] = we17[i];
    __syncthreads();
    int wv = tid >> 6, lane = tid & 63;
    int n = blockIdx.x * 4 + wv;
    float xr8[8], att8[8];
#pragma unroll
    for (int i = 0; i < 8; ++i) {
        int d = lane + i * 64;
        xr8[i] = xr[(size_t)n * D + d];
        att8[i] = att[d];
    }
    int o0 = off[n];
    int deg = off[n + 1] - o0;
    if (deg > 80) deg = 80;
    for (int j = 0; j <= deg; ++j) {
        int er, s;
        if (j < deg) { int e = adj[o0 + j]; er = e; s = ei[e]; }
        else         { er = EE + n; s = n; }
        const float* ep = &ein[(size_t)er * 17];
        float e17[17];
#pragma unroll
        for (int k = 0; k < 17; ++k) e17[k] = ep[k];
        float a = 0;
#pragma unroll
        for (int i = 0; i < 8; ++i) {
            int d = lane + i * 64;
            float m = xl[(size_t)s * D + d] + xr8[i];
#pragma unroll
            for (int k = 0; k < 17; ++k) m += e17[k] * we[k][d];
            m = m > 0.f ? m : 0.2f * m;
            a += att8[i] * m;
        }
        a = wsum(a);
        if (lane == 0) sc[wv][j] = a;
    }
    __syncthreads();
    float mx = -1e30f;
    for (int j = 0; j <= deg; ++j) mx = fmaxf(mx, sc[wv][j]);
    float z = 0;
    for (int j = 0; j <= deg; ++j) z += expf(sc[wv][j] - mx);
    float acc[8] = {};
    for (int j = 0; j <= deg; ++j) {
        int s = (j < deg) ? ei[adj[o0 + j]] : n;
        float w = expf(sc[wv][j] - mx);
#pragma unroll
        for (int i = 0; i < 8; ++i) acc[i] += w * xl[(size_t)s * D + lane + i * 64];
    }
    float inv = 1.f / z;
#pragma unroll
    for (int i = 0; i < 8; ++i) out[(size_t)n * D + lane + i * 64] = acc[i] * inv;
}

// ---------------------------------------------------------------------------
// Ring / mol helpers
// ---------------------------------------------------------------------------
__global__ void gather_rows(const float* __restrict__ src, const int* __restrict__ idx,
                            float* __restrict__ dst, int nrows) {
    int i = blockIdx.x * 256 + threadIdx.x;
    int r = i >> 9;
    if (r >= nrows) return;
    dst[i] = src[(size_t)idx[r] * D + (i & 511)];
}

__global__ __launch_bounds__(256) void ring_attn(
    const float* __restrict__ q, const float* __restrict__ k,
    const float* __restrict__ v, float* __restrict__ o)
{
    int rh = blockIdx.x, r = rh >> 1, hh = rh & 1;
    __shared__ float qs[RS * 256], ks[RS * 256], vs[RS * 256];
    __shared__ float scs[36], pr[36];
    int tid = threadIdx.x;
    size_t base = (size_t)r * RS * D + hh * 256;
    for (int i = tid; i < RS * 256; i += 256) {
        int si = i >> 8, d = i & 255;
        size_t g = base + (size_t)si * D + d;
        qs[i] = q[g]; ks[i] = k[g]; vs[i] = v[g];
    }
    __syncthreads();
    if (tid < 36) {
        int i = tid / 6, j = tid % 6;
        float a = 0;
        for (int d = 0; d < 256; ++d) a += qs[i * 256 + d] * ks[j * 256 + d];
        scs[tid] = a * (1.f / 16.f);
    }
    __syncthreads();
    if (tid < 6) {
        float mx = -1e30f;
        for (int j = 0; j < 6; ++j) mx = fmaxf(mx, scs[tid * 6 + j]);
        float p[6], s = 0;
        for (int j = 0; j < 6; ++j) { p[j] = expf(scs[tid * 6 + j] - mx); s += p[j]; }
        for (int j = 0; j < 6; ++j) pr[tid * 6 + j] = p[j] / s;
    }
    __syncthreads();
    for (int i = tid; i < RS * 256; i += 256) {
        int si = i >> 8, d = i & 255;
        float a = 0;
        for (int j = 0; j < 6; ++j) a += pr[si * 6 + j] * vs[j * 256 + d];
        o[base + (size_t)si * D + d] = a;
    }
}

// mol attention: nh=4, dh=128; 8 queries/block (2 per wave). grid (256, 18)
__global__ __launch_bounds__(256) void mol_attn2(
    const float* __restrict__ q, const float* __restrict__ k,
    const float* __restrict__ v, float* __restrict__ o)
{
    __shared__ float qs[8][128];
    __shared__ float ps[8][140];
    int bh = blockIdx.x, b = bh >> 2, hh = bh & 3;
    int wv = threadIdx.x >> 6, lane = threadIdx.x & 63;
    size_t hb = (size_t)b * SEQS * D + hh * 128;
    int q0 = blockIdx.y * 8;
    for (int i = threadIdx.x; i < 8 * 128; i += 256) {
        int qq = i >> 7, d = i & 127;
        int qi = q0 + qq;
        qs[qq][d] = (qi < SEQS) ? q[hb + (size_t)qi * D + d] : 0.f;
    }
    __syncthreads();
    for (int t = 0; t < 2; ++t) {
        int qq = wv * 2 + t, qi = q0 + qq;
        if (qi >= SEQS) continue;
        float s0[3] = {-1e30f, -1e30f, -1e30f};
#pragma unroll
        for (int jj = 0; jj < 3; ++jj) {
            int j = lane + jj * 64;
            if (j < SEQS) {
                const float* kp = &k[hb + (size_t)j * D];
                float a = 0;
#pragma unroll 8
                for (int d4 = 0; d4 < 32; ++d4) {
                    float4 kv = *(const float4*)&kp[d4 * 4];
                    float4 qv = *(const float4*)&qs[qq][d4 * 4];
                    a += qv.x * kv.x + qv.y * kv.y + qv.z * kv.z + qv.w * kv.w;
                }
                s0[jj] = a * 0.08838834764831845f;
            }
        }
        float mx = wmax(fmaxf(fmaxf(s0[0], s0[1]), s0[2]));
        float lsum = 0;
#pragma unroll
        for (int jj = 0; jj < 3; ++jj) {
            int j = lane + jj * 64;
            if (j < SEQS) { float p = expf(s0[jj] - mx); ps[qq][j] = p; lsum += p; }
        }
        float z = wsum(lsum);
        float a0 = 0, a1 = 0;
        for (int j = 0; j < SEQS; ++j) {
            float p = ps[qq][j];
            const float* vp = &v[hb + (size_t)j * D];
            a0 += p * vp[lane];
            a1 += p * vp[lane + 64];
        }
        float inv = 1.f / z;
        o[hb + (size_t)qi * D + lane]      = a0 * inv;
        o[hb + (size_t)qi * D + lane + 64] = a1 * inv;
    }
}

__global__ void ring_pick(const float* __restrict__ t, float* __restrict__ rv) {
    int i = blockIdx.x * 256 + threadIdx.x;
    if (i >= RGS * D) return;
    int r = i >> 9, d = i & 511;
    const float* p = &t[(size_t)r * RS * D + d];
    float best = p[0], ba = fabsf(best);
#pragma unroll
    for (int s = 1; s < RS; ++s) {
        float x = p[(size_t)s * D];
        float ax = fabsf(x);
        if (ax > ba) { ba = ax; best = x; }
    }
    rv[i] = best;
}

__global__ void assemble(const float* __restrict__ h, const float* __restrict__ rv,
                         const float* __restrict__ cls, const float* __restrict__ ringt,
                         const float* __restrict__ endt, float* __restrict__ seq) {
    int i = blockIdx.x * 256 + threadIdx.x;
    if (i >= NSEQ * D) return;
    int row = i >> 9, d = i & 511;
    int b = row / SEQS, p = row % SEQS;
    float val;
    if (p == 0)        val = cls[d];
    else if (p <= 128) val = h[((size_t)b * 128 + (p - 1)) * D + d];
    else if (p == 129) val = ringt[d];
    else if (p <= 137) val = rv[((size_t)b * 8 + (p - 130)) * D + d];
    else               val = endt[d];
    seq[i] = val;
}

// ---------------------------------------------------------------------------
extern "C" void kernel_launch(void* const* d_in, const int* in_sizes, int n_in,
                              void* d_out, int out_size, void* d_ws, size_t ws_size,
                              hipStream_t stream) {
    (void)in_sizes; (void)n_in; (void)out_size; (void)ws_size;

    const float* x          = (const float*)d_in[0];
    const float* edge_attr  = (const float*)d_in[1];
    const int*   ei         = (const int*)  d_in[2];
    const int*   rings_idx  = (const int*)  d_in[3];
    const float* x_proj_w   = (const float*)d_in[8];
    const float* x_proj_b   = (const float*)d_in[9];
    const float* e_proj_w   = (const float*)d_in[10];
    const float* e_proj_b   = (const float*)d_in[11];
    const float* gat_wl     = (const float*)d_in[12];
    const float* gat_bl     = (const float*)d_in[13];
    const float* gat_wr     = (const float*)d_in[14];
    const float* gat_br     = (const float*)d_in[15];
    const float* gat_we     = (const float*)d_in[16];
    const float* gat_att    = (const float*)d_in[17];
    const float* gat_bias   = (const float*)d_in[18];
    const float* gat_ln     = (const float*)d_in[19];
    const float* ring_attn_w= (const float*)d_in[20];
    const float* ring_attn_b= (const float*)d_in[21];
    const float* ring_w1    = (const float*)d_in[22];
    const float* ring_b1    = (const float*)d_in[23];
    const float* ring_w2    = (const float*)d_in[24];
    const float* ring_b2    = (const float*)d_in[25];
    const float* ring_ln    = (const float*)d_in[26];
    const float* mol_attn_w = (const float*)d_in[27];
    const float* mol_attn_b = (const float*)d_in[28];
    const float* mol_w1     = (const float*)d_in[29];
    const float* mol_b1     = (const float*)d_in[30];
    const float* mol_w2     = (const float*)d_in[31];
    const float* mol_b2     = (const float*)d_in[32];
    const float* mol_ln     = (const float*)d_in[33];
    const float* cls_tok    = (const float*)d_in[34];
    const float* ring_tok   = (const float*)d_in[35];
    const float* end_tok    = (const float*)d_in[36];

    constexpr size_t MB = 1024 * 1024;
    char* wsb = (char*)d_ws;
#define WSF(off) ((float*)(wsb + (size_t)(off)))
#define WSI(off) ((int*)(wsb + (size_t)(off)))
#define WSU(off) ((unsigned short*)(wsb + (size_t)(off)))

    // ---- GAT phase ----
    float* H    = WSF(0);                 // [8192,512] persists through mol assemble
    float* XL   = WSF(16 * MB);
    float* XR   = WSF(32 * MB);
    float* HN   = WSF(48 * MB);
    float* EIN  = WSF(64 * MB);
    float* WE17 = WSF(67 * MB);
    float* AGG  = WSF(68 * MB);
    int*   DEGI = WSI(68 * MB + 512 * 1024);
    int*   OFF  = WSI(68 * MB + 576 * 1024);
    int*   CNT  = WSI(68 * MB + 640 * 1024);
    int*   ADJ  = WSI(68 * MB + 704 * 1024);
    float* RVEC = WSF(70 * MB);

    // ---- ring phase (dead after ring_pick) ----
    float* T    = WSF(71 * MB);
    float* RQ   = WSF(77 * MB);
    float* RK   = WSF(83 * MB);
    float* RV   = WSF(89 * MB);
    float* RO   = WSF(95 * MB);
    float* RTMP = WSF(101 * MB);
    float* RY   = WSF(107 * MB);
    float* RFF  = WSF(113 * MB);
    float* RT2  = WSF(137 * MB);

    // ---- mol phase (MHAT=8960 padded rows) ----
    float* SEQ  = WSF(71 * MB);            // 17.5MB, dead after first LN
    float* MQ   = WSF(89 * MB);            // 17.5
    float* MK   = WSF(107 * MB);
    float* MV   = WSF(125 * MB);
    float* MO   = WSF(143 * MB);           // ends 160.5
    unsigned short* ACTh = WSU(161 * MB);  // [8960,512] bf16 = 8.75MB
    unsigned short* ACTl = WSU(170 * MB);
    // weight splits @179MB
    unsigned short* WQh = WSU(179 * MB);            unsigned short* WQl = WSU(179 * MB + 512 * 1024);
    unsigned short* WKh = WSU(180 * MB);            unsigned short* WKl = WSU(180 * MB + 512 * 1024);
    unsigned short* WVh = WSU(181 * MB);            unsigned short* WVl = WSU(181 * MB + 512 * 1024);
    unsigned short* WOh = WSU(182 * MB);            unsigned short* WOl = WSU(182 * MB + 512 * 1024);
    unsigned short* W1h = WSU(183 * MB);            unsigned short* W1l = WSU(185 * MB);   // [2048,512] 2MB
    unsigned short* W2h = WSU(187 * MB);            unsigned short* W2l = WSU(189 * MB);   // [512,2048] 2MB
    float* MTMP = WSF(89 * MB);            // = MQ region (dead after attn)
    float* MY   = WSF(107 * MB);           // = MK region (dead after attn)
    unsigned short* MFFh = WSU(125 * MB);  // [8960,2048] bf16 = 35MB (MV/MO dead)
    unsigned short* MFFl = WSU(16 * MB);   // 35MB over XL/XR/HN (dead)
    float* MT2  = WSF(71 * MB);            // = SEQ region (dead)

    dim3 blk(256);
    auto gemm = [&](const float* A, const float* B, const float* bias, float* C,
                    int M, int Nc, int K, int flags) {
        gemm128<<<dim3((M + 127) / 128, Nc / 128), blk, 0, stream>>>(A, B, bias, C, M, Nc, K, flags);
    };
    auto gemm3 = [&](const unsigned short* AhP, const unsigned short* AlP,
                     const unsigned short* BhP, const unsigned short* BlP,
                     const float* bias, float* C, unsigned short* ChP, unsigned short* ClP,
                     int Nc, int K, int flags) {
        gemm_split3<<<dim3(MHAT / 128, Nc / 128), blk, 0, stream>>>(
            AhP, AlP, BhP, BlP, bias, C, ChP, ClP, Nc, K, flags);
    };

    // ---- phase 0: graph preprocessing ----
    hipMemsetAsync(DEGI, 0, NN * 4, stream);
    hipMemsetAsync(CNT, 0, NN * 4, stream);
    hipMemsetAsync(AGG, 0, (size_t)NN * 16 * 4, stream);
    deg_int<<<EE / 256, blk, 0, stream>>>(ei, DEGI);
    scan_deg<<<1, blk, 0, stream>>>(DEGI, OFF);
    csr_fill<<<EE / 256, blk, 0, stream>>>(ei, CNT, OFF, ADJ);
    eagg_acc<<<EE * 16 / 256, blk, 0, stream>>>(edge_attr, ei, AGG);
    ein_build<<<ENL / 256, blk, 0, stream>>>(edge_attr, AGG, DEGI, EIN);

    // ---- phase 1: x projection ----
    gemm(x, x_proj_w, x_proj_b, H, NN, D, 64, 1);

    // ---- phase 2: 6x GATv2 (f32, precision-critical) ----
    for (int l = 0; l < 6; ++l) {
        we17_build<<<2, blk, 0, stream>>>(e_proj_w, e_proj_b,
                                          gat_we + (size_t)l * D * D, WE17);
        gemm(H, gat_wl + (size_t)l * D * D, gat_bl + l * D, XL, NN, D, D, 1);
        gemm(H, gat_wr + (size_t)l * D * D, gat_br + l * D, XR, NN, D, D, 1);
        gat_node<<<NN / 4, blk, 0, stream>>>(XL, XR, EIN, WE17, OFF, ADJ, ei,
                                             gat_att + l * D, HN);
        if (l < 5) {
            ln_rows<<<NN / 4, blk, 0, stream>>>(HN, nullptr, gat_bias + l * D,
                gat_ln + (size_t)l * 2 * D, gat_ln + (size_t)l * 2 * D + D, H, NN, 3);
        } else {
            ln_rows<<<NN / 4, blk, 0, stream>>>(HN, nullptr, gat_bias + l * D,
                nullptr, nullptr, H, NN, 0);
        }
    }

    // ---- phase 3: ring encoder (f32, precision-critical) ----
    const int RROWS = RGS * RS;
    gather_rows<<<RROWS * D / 256, blk, 0, stream>>>(H, rings_idx, T, RROWS);
    gemm(T, ring_attn_w + 0 * D * D, ring_attn_b + 0 * D, RQ, RROWS, D, D, 1);
    gemm(T, ring_attn_w + 1 * D * D, ring_attn_b + 1 * D, RK, RROWS, D, D, 1);
    gemm(T, ring_attn_w + 2 * D * D, ring_attn_b + 2 * D, RV, RROWS, D, D, 1);
    ring_attn<<<RGS * 2, blk, 0, stream>>>(RQ, RK, RV, RO);
    gemm(RO, ring_attn_w + 3 * D * D, ring_attn_b + 3 * D, RTMP, RROWS, D, D, 1);
    ln_rows<<<RROWS / 4, blk, 0, stream>>>(RTMP, T, nullptr, ring_ln, ring_ln + D, RY, RROWS, 2);
    gemm(RY, ring_w1, ring_b1, RFF, RROWS, DFF, D, 3);
    gemm(RFF, ring_w2, ring_b2, RTMP, RROWS, D, DFF, 1);
    ln_rows<<<RROWS / 4, blk, 0, stream>>>(RTMP, RY, nullptr, ring_ln + 2 * D, ring_ln + 3 * D, RT2, RROWS, 2);
    ring_pick<<<RGS * D / 256, blk, 0, stream>>>(RT2, RVEC);

    // ---- phase 4: mol encoder (MFMA bf16x3 split) ----
    assemble<<<(NSEQ * D) / 256, blk, 0, stream>>>(H, RVEC, cls_tok, ring_tok, end_tok, SEQ);
    // weight splits
    wsplitT<<<(D * D + 255) / 256, blk, 0, stream>>>(mol_attn_w + 0 * D * D, WQh, WQl, D, D);
    wsplitT<<<(D * D + 255) / 256, blk, 0, stream>>>(mol_attn_w + 1 * D * D, WKh, WKl, D, D);
    wsplitT<<<(D * D + 255) / 256, blk, 0, stream>>>(mol_attn_w + 2 * D * D, WVh, WVl, D, D);
    wsplitT<<<(D * D + 255) / 256, blk, 0, stream>>>(mol_attn_w + 3 * D * D, WOh, WOl, D, D);
    wsplitT<<<(D * DFF + 255) / 256, blk, 0, stream>>>(mol_w1, W1h, W1l, D, DFF);
    wsplitT<<<(DFF * D + 255) / 256, blk, 0, stream>>>(mol_w2, W2h, W2l, DFF, D);

    const int N4_512 = MHAT * D / 4;
    asplit4<<<(N4_512 + 255) / 256, blk, 0, stream>>>(SEQ, ACTh, ACTl, N4_512);
    gemm3(ACTh, ACTl, WQh, WQl, mol_attn_b + 0 * D, MQ, nullptr, nullptr, D, D, 1);
    gemm3(ACTh, ACTl, WKh, WKl, mol_attn_b + 1 * D, MK, nullptr, nullptr, D, D, 1);
    gemm3(ACTh, ACTl, WVh, WVl, mol_attn_b + 2 * D, MV, nullptr, nullptr, D, D, 1);
    mol_attn2<<<dim3(BMOL * 4, (SEQS + 7) / 8), blk, 0, stream>>>(MQ, MK, MV, MO);
    asplit4<<<(N4_512 + 255) / 256, blk, 0, stream>>>(MO, ACTh, ACTl, N4_512);
    gemm3(ACTh, ACTl, WOh, WOl, mol_attn_b + 3 * D, MTMP, nullptr, nullptr, D, D, 1);
    ln_rows<<<(NSEQ + 3) / 4, blk, 0, stream>>>(MTMP, SEQ, nullptr, mol_ln, mol_ln + D, MY, NSEQ, 2);
    asplit4<<<(N4_512 + 255) / 256, blk, 0, stream>>>(MY, ACTh, ACTl, N4_512);
    gemm3(ACTh, ACTl, W1h, W1l, mol_b1, nullptr, MFFh, MFFl, DFF, D, 1 | 2 | 4);
    gemm3(MFFh, MFFl, W2h, W2l, mol_b2, MT2, nullptr, nullptr, D, DFF, 1);

    float* outf = (float*)d_out;
    ln_rows<<<(NSEQ + 3) / 4, blk, 0, stream>>>(MT2, MY, nullptr, mol_ln + 2 * D, mol_ln + 3 * D, outf, NSEQ, 2);
    fill_f32<<<(BMOL * 128 + BMOL * 8 + 255) / 256, blk, 0, stream>>>(
        outf + (size_t)NSEQ * D, 1.0f, BMOL * 128 + BMOL * 8);
}

// Round 5
// 2317.859 us; speedup vs baseline: 2.8484x; 1.6926x over previous
//
#include <hip/hip_runtime.h>
#include <math.h>

// ---------------------------------------------------------------------------
// Round 5: occupancy + locality.
//  - gemm_f32b: batched (shared-A, grid.z) + split-K f32 GEMM; ln_rows folds
//    split-K partials (+bias) exactly in f32.
//  - mol_attn3: fused per-(b,h) attention, K/V staged once in f16 LDS
//    (79 KB dynamic, 2 blocks/CU), 2 queries/wave, v_dot2_f32_f16.
//  - we17_build hoisted out of the GAT layer loop, k-parallel.
//  - mol QKV split3 GEMMs batched via grid.z.
// Precision: GAT+ring stay f32 (ring_pick abs-argmax amplifier); mol phase
// tolerates bf16x3 / f16 noise (threshold 0.093, current absmax 0.0156).
// ---------------------------------------------------------------------------

#define DEV __device__ __forceinline__

constexpr int NN   = 8192;
constexpr int EE   = 32768;
constexpr int ENL  = EE + NN;
constexpr int D    = 512;
constexpr int RGS  = 512;
constexpr int RS   = 6;
constexpr int BMOL = 64;
constexpr int SEQS = 139;
constexpr int NSEQ = BMOL * SEQS;  // 8896
constexpr int MHAT = 8960;         // 70 tiles of 128
constexpr int DFF  = 2048;

typedef short bf8 __attribute__((ext_vector_type(8)));
typedef float f32x4 __attribute__((ext_vector_type(4)));
typedef _Float16 half2_t __attribute__((ext_vector_type(2)));
typedef _Float16 half8_t __attribute__((ext_vector_type(8)));

#ifdef __has_builtin
#if __has_builtin(__builtin_amdgcn_fdot2)
#define HAS_FDOT2 1
#endif
#endif
#ifndef HAS_FDOT2
#define HAS_FDOT2 0
#endif

DEV float wsum(float v) {
    for (int o = 32; o > 0; o >>= 1) v += __shfl_xor(v, o, 64);
    return v;
}
DEV float wmax(float v) {
    for (int o = 32; o > 0; o >>= 1) v = fmaxf(v, __shfl_xor(v, o, 64));
    return v;
}
DEV unsigned short f2bf(float x) {
    unsigned u = __float_as_uint(x);
    u += 0x7FFFu + ((u >> 16) & 1u);
    return (unsigned short)(u >> 16);
}
DEV float bf2f(unsigned short h) { return __uint_as_float((unsigned)h << 16); }

DEV float dot8(half8_t a, half8_t b, float acc) {
#if HAS_FDOT2
    acc = __builtin_amdgcn_fdot2(__builtin_shufflevector(a, a, 0, 1),
                                 __builtin_shufflevector(b, b, 0, 1), acc, false);
    acc = __builtin_amdgcn_fdot2(__builtin_shufflevector(a, a, 2, 3),
                                 __builtin_shufflevector(b, b, 2, 3), acc, false);
    acc = __builtin_amdgcn_fdot2(__builtin_shufflevector(a, a, 4, 5),
                                 __builtin_shufflevector(b, b, 4, 5), acc, false);
    acc = __builtin_amdgcn_fdot2(__builtin_shufflevector(a, a, 6, 7),
                                 __builtin_shufflevector(b, b, 6, 7), acc, false);
#else
#pragma unroll
    for (int i = 0; i < 8; ++i) acc += (float)a[i] * (float)b[i];
#endif
    return acc;
}

// ---------------------------------------------------------------------------
// Batched / split-K f32 GEMM. 128x128 tile, 8x8/thread.
// grid.z = nb * kparts; z -> (batch b, k-part kp). Bias only when kparts==1.
// ---------------------------------------------------------------------------
struct GB {
    const float* A;
    const float* B0; const float* B1; const float* B2;
    const float* bias0; const float* bias1; const float* bias2;
    float* C0; float* C1; float* C2;
    int M, N, K, flags, kparts, ksz;
    long long cstride;   // elements between k-partials
};

__global__ __launch_bounds__(256) void gemm_f32b(GB g) {
    __shared__ float As[16][132];
    __shared__ float Bs[16][128];
    const int z = blockIdx.z;
    const int bb = z / g.kparts, kp = z % g.kparts;
    const float* B = bb == 0 ? g.B0 : (bb == 1 ? g.B1 : g.B2);
    const float* bias = bb == 0 ? g.bias0 : (bb == 1 ? g.bias1 : g.bias2);
    float* C = (bb == 0 ? g.C0 : (bb == 1 ? g.C1 : g.C2)) + (size_t)kp * g.cstride;
    const int M = g.M, N = g.N;

    const int tid = threadIdx.x;
    const int wv = tid >> 6, ln = tid & 63;
    const int mg = ((ln >> 3) & 7) | ((wv & 1) << 3);
    const int ng = (ln & 7) | ((wv >> 1) << 3);
    const int m0 = blockIdx.x * 128, n0 = blockIdx.y * 128;

    const int a_row = tid >> 2;
    const int a_kg  = tid & 3;
    const int b_row = tid >> 5;
    const int b_cg  = tid & 31;

    float acc[8][8] = {};
    const int kbeg = kp * g.ksz, kend = kbeg + g.ksz;
    for (int k0 = kbeg; k0 < kend; k0 += 16) {
#pragma unroll
        for (int i = 0; i < 2; ++i) {
            int r = a_row + i * 64;
            int gr = m0 + r; if (gr >= M) gr = M - 1;
            float4 av = *(const float4*)&g.A[(size_t)gr * g.K + k0 + a_kg * 4];
            As[a_kg * 4 + 0][r] = av.x;
            As[a_kg * 4 + 1][r] = av.y;
            As[a_kg * 4 + 2][r] = av.z;
            As[a_kg * 4 + 3][r] = av.w;
        }
#pragma unroll
        for (int i = 0; i < 2; ++i) {
            int r = b_row + i * 8;
            float4 bv = *(const float4*)&B[(size_t)(k0 + r) * N + n0 + b_cg * 4];
            *(float4*)&Bs[r][b_cg * 4] = bv;
        }
        __syncthreads();
#pragma unroll
        for (int k = 0; k < 16; ++k) {
            float a0[8], b0[8];
            *(float4*)&a0[0] = *(const float4*)&As[k][mg * 8];
            *(float4*)&a0[4] = *(const float4*)&As[k][mg * 8 + 4];
            *(float4*)&b0[0] = *(const float4*)&Bs[k][ng * 8];
            *(float4*)&b0[4] = *(const float4*)&Bs[k][ng * 8 + 4];
#pragma unroll
            for (int i = 0; i < 8; ++i)
#pragma unroll
                for (int j = 0; j < 8; ++j) acc[i][j] += a0[i] * b0[j];
        }
        __syncthreads();
    }
#pragma unroll
    for (int i = 0; i < 8; ++i) {
        int gr = m0 + mg * 8 + i;
        if (gr >= M) break;
        float* cp = &C[(size_t)gr * N + n0 + ng * 8];
        float o[8];
#pragma unroll
        for (int j = 0; j < 8; ++j) o[j] = acc[i][j];
        if ((g.flags & 1) && g.kparts == 1) {
            const float* bp = bias + n0 + ng * 8;
#pragma unroll
            for (int j = 0; j < 8; ++j) o[j] += bp[j];
        }
        if (g.flags & 2) {
#pragma unroll
            for (int j = 0; j < 8; ++j) o[j] = fmaxf(o[j], 0.f);
        }
        *(float4*)&cp[0] = make_float4(o[0], o[1], o[2], o[3]);
        *(float4*)&cp[4] = make_float4(o[4], o[5], o[6], o[7]);
    }
}

// ---------------------------------------------------------------------------
// MFMA bf16x3-split GEMM (mol phase). Batched via grid.z with strides.
// ---------------------------------------------------------------------------
__global__ __launch_bounds__(256) void gemm_split3(
    const unsigned short* __restrict__ Ah, const unsigned short* __restrict__ Al,
    const unsigned short* __restrict__ Bh, const unsigned short* __restrict__ Bl,
    const float* __restrict__ bias, float* __restrict__ C,
    unsigned short* __restrict__ Ch, unsigned short* __restrict__ Cl,
    int N, int K, int flags, long long bstride, long long cstride, int biasstride)
{
    __shared__ unsigned short sA[2][128][40];
    __shared__ unsigned short sB[2][128][40];
    const int z = blockIdx.z;
    Bh += (size_t)z * bstride; Bl += (size_t)z * bstride;
    if (bias) bias += (size_t)z * biasstride;
    if (C) C += (size_t)z * cstride;
    const int tid = threadIdx.x;
    const int wv = tid >> 6, lane = tid & 63;
    const int m0 = blockIdx.x * 128, n0 = blockIdx.y * 128;
    const int srow = tid >> 2, sc8 = (tid & 3) * 8;
    const int mw = (wv & 1) * 64, nw = (wv >> 1) * 64;
    const int fr = lane & 15, fq = lane >> 4;
    const int ko = fq * 8;

    f32x4 acc[4][4];
    f32x4 zero = {0.f, 0.f, 0.f, 0.f};
#pragma unroll
    for (int i = 0; i < 4; ++i)
#pragma unroll
        for (int j = 0; j < 4; ++j) acc[i][j] = zero;

    for (int k0 = 0; k0 < K; k0 += 32) {
#pragma unroll
        for (int h = 0; h < 2; ++h) {
            int r = srow + h * 64;
            *(bf8*)&sA[0][r][sc8] = *(const bf8*)&Ah[(size_t)(m0 + r) * K + k0 + sc8];
            *(bf8*)&sA[1][r][sc8] = *(const bf8*)&Al[(size_t)(m0 + r) * K + k0 + sc8];
            *(bf8*)&sB[0][r][sc8] = *(const bf8*)&Bh[(size_t)(n0 + r) * K + k0 + sc8];
            *(bf8*)&sB[1][r][sc8] = *(const bf8*)&Bl[(size_t)(n0 + r) * K + k0 + sc8];
        }
        __syncthreads();
        bf8 ah[4], al[4], bh[4], bl[4];
#pragma unroll
        for (int t = 0; t < 4; ++t) {
            ah[t] = *(const bf8*)&sA[0][mw + t * 16 + fr][ko];
            al[t] = *(const bf8*)&sA[1][mw + t * 16 + fr][ko];
            bh[t] = *(const bf8*)&sB[0][nw + t * 16 + fr][ko];
            bl[t] = *(const bf8*)&sB[1][nw + t * 16 + fr][ko];
        }
#pragma unroll
        for (int i = 0; i < 4; ++i)
#pragma unroll
            for (int j = 0; j < 4; ++j) {
                acc[i][j] = __builtin_amdgcn_mfma_f32_16x16x32_bf16(ah[i], bh[j], acc[i][j], 0, 0, 0);
                acc[i][j] = __builtin_amdgcn_mfma_f32_16x16x32_bf16(ah[i], bl[j], acc[i][j], 0, 0, 0);
                acc[i][j] = __builtin_amdgcn_mfma_f32_16x16x32_bf16(al[i], bh[j], acc[i][j], 0, 0, 0);
            }
        __syncthreads();
    }
#pragma unroll
    for (int i = 0; i < 4; ++i)
#pragma unroll
        for (int j = 0; j < 4; ++j) {
            int col = n0 + nw + j * 16 + fr;
#pragma unroll
            for (int r = 0; r < 4; ++r) {
                int row = m0 + mw + i * 16 + fq * 4 + r;
                float o = acc[i][j][r];
                if (flags & 1) o += bias[col];
                if (flags & 2) o = fmaxf(o, 0.f);
                size_t idx = (size_t)row * N + col;
                if (flags & 4) {
                    unsigned short hb_ = f2bf(o);
                    Ch[idx] = hb_;
                    Cl[idx] = f2bf(o - bf2f(hb_));
                } else {
                    C[idx] = o;
                }
            }
        }
}

__global__ void asplit4(const float* __restrict__ src, unsigned short* __restrict__ hh,
                        unsigned short* __restrict__ ll, int n4) {
    int i = blockIdx.x * 256 + threadIdx.x;
    if (i >= n4) return;
    float4 v = ((const float4*)src)[i];
    ushort4 h, l;
    h.x = f2bf(v.x); l.x = f2bf(v.x - bf2f(h.x));
    h.y = f2bf(v.y); l.y = f2bf(v.y - bf2f(h.y));
    h.z = f2bf(v.z); l.z = f2bf(v.z - bf2f(h.z));
    h.w = f2bf(v.w); l.w = f2bf(v.w - bf2f(h.w));
    ((ushort4*)hh)[i] = h;
    ((ushort4*)ll)[i] = l;
}

__global__ void wsplitT(const float* __restrict__ w, unsigned short* __restrict__ bh,
                        unsigned short* __restrict__ bl, int K, int N) {
    int i = blockIdx.x * 256 + threadIdx.x;
    if (i >= K * N) return;
    int k = i / N, n = i - k * N;
    float x = w[i];
    unsigned short h = f2bf(x);
    unsigned short l = f2bf(x - bf2f(h));
    bh[(size_t)n * K + k] = h;
    bl[(size_t)n * K + k] = l;
}

// ---------------------------------------------------------------------------
// Row LayerNorm (D=512), wave per row. flags: 1 relu, 2 LN. parts: sum
// split-K partials x[p][rows][D] before (res, bias, LN).
// ---------------------------------------------------------------------------
__global__ __launch_bounds__(256) void ln_rows(
    const float* __restrict__ x, const float* __restrict__ res,
    const float* __restrict__ bias, const float* __restrict__ g,
    const float* __restrict__ be, float* __restrict__ out, int rows, int flags,
    int parts)
{
    int r = blockIdx.x * 4 + (threadIdx.x >> 6);
    if (r >= rows) return;
    int lane = threadIdx.x & 63;
    size_t base = (size_t)r * D;
    size_t pstride = (size_t)rows * D;
    float v[8];
#pragma unroll
    for (int i = 0; i < 8; ++i) {
        int d = lane + i * 64;
        float t = x[base + d];
        for (int p = 1; p < parts; ++p) t += x[p * pstride + base + d];
        if (res)  t += res[base + d];
        if (bias) t += bias[d];
        v[i] = t;
    }
    if (flags & 2) {
        float s = 0;
#pragma unroll
        for (int i = 0; i < 8; ++i) s += v[i];
        float mu = wsum(s) * (1.f / 512.f);
        float q = 0;
#pragma unroll
        for (int i = 0; i < 8; ++i) { float d0 = v[i] - mu; q += d0 * d0; }
        float inv = rsqrtf(wsum(q) * (1.f / 512.f) + 1e-5f);
#pragma unroll
        for (int i = 0; i < 8; ++i) {
            int d = lane + i * 64;
            float o = (v[i] - mu) * inv * g[d] + be[d];
            if (flags & 1) o = fmaxf(o, 0.f);
            out[base + d] = o;
        }
    } else {
#pragma unroll
        for (int i = 0; i < 8; ++i) {
            int d = lane + i * 64;
            float o = v[i];
            if (flags & 1) o = fmaxf(o, 0.f);
            out[base + d] = o;
        }
    }
}

__global__ void fill_f32(float* p, float v, int n) {
    int i = blockIdx.x * 256 + threadIdx.x;
    if (i < n) p[i] = v;
}

// ---------------------------------------------------------------------------
// Graph preprocessing
// ---------------------------------------------------------------------------
__global__ void deg_int(const int* __restrict__ ei, int* __restrict__ degi) {
    int e = blockIdx.x * 256 + threadIdx.x;
    if (e >= EE) return;
    atomicAdd(&degi[ei[EE + e]], 1);
}

__global__ __launch_bounds__(256) void scan_deg(const int* __restrict__ degi,
                                                int* __restrict__ off) {
    __shared__ int ps[256];
    int tid = threadIdx.x;
    int base = tid * 32;
    int loc[32];
    int s = 0;
#pragma unroll
    for (int i = 0; i < 32; ++i) { loc[i] = s; s += degi[base + i]; }
    ps[tid] = s;
    __syncthreads();
    for (int o = 1; o < 256; o <<= 1) {
        int v = (tid >= o) ? ps[tid - o] : 0;
        __syncthreads();
        ps[tid] += v;
        __syncthreads();
    }
    int pre = (tid == 0) ? 0 : ps[tid - 1];
#pragma unroll
    for (int i = 0; i < 32; ++i) off[base + i] = pre + loc[i];
    if (tid == 255) off[8192] = ps[255];
}

__global__ void csr_fill(const int* __restrict__ ei, int* __restrict__ cnt,
                         const int* __restrict__ off, int* __restrict__ adj) {
    int e = blockIdx.x * 256 + threadIdx.x;
    if (e >= EE) return;
    int dn = ei[EE + e];
    int p = atomicAdd(&cnt[dn], 1);
    adj[off[dn] + p] = e;
}

__global__ void eagg_acc(const float* __restrict__ eattr, const int* __restrict__ ei,
                         float* __restrict__ agg) {
    int id = blockIdx.x * 256 + threadIdx.x;
    if (id >= EE * 16) return;
    int e = id >> 4, c = id & 15;
    atomicAdd(&agg[(size_t)ei[EE + e] * 16 + c], eattr[id]);
}

__global__ void ein_build(const float* __restrict__ eattr, const float* __restrict__ agg,
                          const int* __restrict__ degi, float* __restrict__ ein) {
    int r = blockIdx.x * 256 + threadIdx.x;
    if (r >= ENL) return;
    float* o = &ein[(size_t)r * 17];
    if (r < EE) {
        const float* a = &eattr[(size_t)r * 16];
#pragma unroll
        for (int k = 0; k < 16; ++k) o[k] = a[k];
        o[16] = 1.f;
    } else {
        int n = r - EE;
        int dg = degi[n];
        float inv = 1.f / (float)(dg > 1 ? dg : 1);
        const float* a = &agg[(size_t)n * 16];
#pragma unroll
        for (int k = 0; k < 16; ++k) o[k] = a[k] * inv;
        o[16] = dg > 0 ? 1.f : 0.f;
    }
}

// all-layer WE17: grid (2, 4, 6); atomicAdd partial k-quarters
__global__ __launch_bounds__(256) void we17_build(
    const float* __restrict__ epw, const float* __restrict__ epb,
    const float* __restrict__ we_all, float* __restrict__ we17_all) {
    int j = blockIdx.x * 256 + threadIdx.x;
    int kk = blockIdx.y, l = blockIdx.z;
    const float* we = we_all + (size_t)l * D * D;
    float* we17 = we17_all + (size_t)l * 17 * D;
    float acc[17];
#pragma unroll
    for (int i = 0; i < 17; ++i) acc[i] = 0.f;
    for (int k = kk * 128; k < kk * 128 + 128; ++k) {
        float wkj = we[(size_t)k * 512 + j];
#pragma unroll
        for (int i = 0; i < 16; ++i) acc[i] += epw[(size_t)i * 512 + k] * wkj;
        acc[16] += epb[k] * wkj;
    }
#pragma unroll
    for (int i = 0; i < 17; ++i) atomicAdd(&we17[(size_t)i * 512 + j], acc[i]);
}

// ---------------------------------------------------------------------------
// GATv2 per-node
// ---------------------------------------------------------------------------
__global__ __launch_bounds__(256) void gat_node(
    const float* __restrict__ xl, const float* __restrict__ xr,
    const float* __restrict__ ein, const float* __restrict__ we17,
    const int* __restrict__ off, const int* __restrict__ adj,
    const int* __restrict__ ei, const float* __restrict__ att,
    float* __restrict__ out)
{
    __shared__ float we[17][512];
    __shared__ float sc[4][88];
    int tid = threadIdx.x;
    for (int i = tid; i < 17 * 512; i += 256) we[i >> 9][i & 511] = we17[i];
    __syncthreads();
    int wv = tid >> 6, lane = tid & 63;
    int n = blockIdx.x * 4 + wv;
    float xr8[8], att8[8];
#pragma unroll
    for (int i = 0; i < 8; ++i) {
        int d = lane + i * 64;
        xr8[i] = xr[(size_t)n * D + d];
        att8[i] = att[d];
    }
    int o0 = off[n];
    int deg = off[n + 1] - o0;
    if (deg > 80) deg = 80;
    for (int j = 0; j <= deg; ++j) {
        int er, s;
        if (j < deg) { int e = adj[o0 + j]; er = e; s = ei[e]; }
        else         { er = EE + n; s = n; }
        const float* ep = &ein[(size_t)er * 17];
        float e17[17];
#pragma unroll
        for (int k = 0; k < 17; ++k) e17[k] = ep[k];
        float a = 0;
#pragma unroll
        for (int i = 0; i < 8; ++i) {
            int d = lane + i * 64;
            float m = xl[(size_t)s * D + d] + xr8[i];
#pragma unroll
            for (int k = 0; k < 17; ++k) m += e17[k] * we[k][d];
            m = m > 0.f ? m : 0.2f * m;
            a += att8[i] * m;
        }
        a = wsum(a);
        if (lane == 0) sc[wv][j] = a;
    }
    __syncthreads();
    float mx = -1e30f;
    for (int j = 0; j <= deg; ++j) mx = fmaxf(mx, sc[wv][j]);
    float z = 0;
    for (int j = 0; j <= deg; ++j) z += expf(sc[wv][j] - mx);
    float acc[8] = {};
    for (int j = 0; j <= deg; ++j) {
        int s = (j < deg) ? ei[adj[o0 + j]] : n;
        float w = expf(sc[wv][j] - mx);
#pragma unroll
        for (int i = 0; i < 8; ++i) acc[i] += w * xl[(size_t)s * D + lane + i * 64];
    }
    float inv = 1.f / z;
#pragma unroll
    for (int i = 0; i < 8; ++i) out[(size_t)n * D + lane + i * 64] = acc[i] * inv;
}

// ---------------------------------------------------------------------------
// Ring helpers
// ---------------------------------------------------------------------------
__global__ void gather_rows(const float* __restrict__ src, const int* __restrict__ idx,
                            float* __restrict__ dst, int nrows) {
    int i = blockIdx.x * 256 + threadIdx.x;
    int r = i >> 9;
    if (r >= nrows) return;
    dst[i] = src[(size_t)idx[r] * D + (i & 511)];
}

__global__ __launch_bounds__(256) void ring_attn(
    const float* __restrict__ q, const float* __restrict__ k,
    const float* __restrict__ v, float* __restrict__ o)
{
    int rh = blockIdx.x, r = rh >> 1, hh = rh & 1;
    __shared__ float qs[RS * 256], ks[RS * 256], vs[RS * 256];
    __shared__ float scs[36], pr[36];
    int tid = threadIdx.x;
    size_t base = (size_t)r * RS * D + hh * 256;
    for (int i = tid; i < RS * 256; i += 256) {
        int si = i >> 8, d = i & 255;
        size_t g = base + (size_t)si * D + d;
        qs[i] = q[g]; ks[i] = k[g]; vs[i] = v[g];
    }
    __syncthreads();
    if (tid < 36) {
        int i = tid / 6, j = tid % 6;
        float a = 0;
        for (int d = 0; d < 256; ++d) a += qs[i * 256 + d] * ks[j * 256 + d];
        scs[tid] = a * (1.f / 16.f);
    }
    __syncthreads();
    if (tid < 6) {
        float mx = -1e30f;
        for (int j = 0; j < 6; ++j) mx = fmaxf(mx, scs[tid * 6 + j]);
        float p[6], s = 0;
        for (int j = 0; j < 6; ++j) { p[j] = expf(scs[tid * 6 + j] - mx); s += p[j]; }
        for (int j = 0; j < 6; ++j) pr[tid * 6 + j] = p[j] / s;
    }
    __syncthreads();
    for (int i = tid; i < RS * 256; i += 256) {
        int si = i >> 8, d = i & 255;
        float a = 0;
        for (int j = 0; j < 6; ++j) a += pr[si * 6 + j] * vs[j * 256 + d];
        o[base + (size_t)si * D + d] = a;
    }
}

// ---------------------------------------------------------------------------
// mol_attn3: fused per-(b,h). K swizzled f16 LDS, V transposed f16 LDS,
// 2 queries per wave per iteration. Dynamic LDS 78848 B (2 blocks/CU).
// ---------------------------------------------------------------------------
constexpr int ATT_K_H  = SEQS * 128;        // 17792 halves
constexpr int ATT_V_ROW = 152;
constexpr int ATT_V_H  = 128 * ATT_V_ROW;   // 19456 halves
constexpr int ATT_PS_ROW = 144;
constexpr int ATT_PS_H = 8 * ATT_PS_ROW;    // 1152 halves
constexpr int ATT_SMEM = (ATT_K_H + ATT_V_H + ATT_PS_H) * 2 + 8 * 64 * 4;  // 78848 B

__global__ __launch_bounds__(256) void mol_attn3(
    const float* __restrict__ q, const float* __restrict__ k,
    const float* __restrict__ v, float* __restrict__ o)
{
    extern __shared__ char smem[];
    _Float16* Ksh = (_Float16*)smem;
    _Float16* Vt  = Ksh + ATT_K_H;
    _Float16* ps  = Vt + ATT_V_H;
    half2_t*  qs  = (half2_t*)(ps + ATT_PS_H);
    const int tid = threadIdx.x, wv = tid >> 6, lane = tid & 63;
    const int b = blockIdx.x >> 2, hh = blockIdx.x & 3;
    const size_t hb = (size_t)b * SEQS * D + hh * 128;

    // stage K: granule (8 halves) g stored at g ^ (j&7) within the row
    for (int i = tid; i < SEQS * 32; i += 256) {
        int j = i >> 5, d4 = i & 31;
        float4 kv = *(const float4*)&k[hb + (size_t)j * D + d4 * 4];
        int off = j * 128 + (((d4 >> 1) ^ (j & 7)) << 3) + ((d4 & 1) << 2);
        *(half2_t*)(Ksh + off)     = half2_t{(_Float16)kv.x, (_Float16)kv.y};
        *(half2_t*)(Ksh + off + 2) = half2_t{(_Float16)kv.z, (_Float16)kv.w};
    }
    // stage V transposed [d][j]
    for (int i = tid; i < SEQS * 32; i += 256) {
        int j = i >> 5, d4 = i & 31;
        float4 vv = *(const float4*)&v[hb + (size_t)j * D + d4 * 4];
        Vt[(d4 * 4 + 0) * ATT_V_ROW + j] = (_Float16)vv.x;
        Vt[(d4 * 4 + 1) * ATT_V_ROW + j] = (_Float16)vv.y;
        Vt[(d4 * 4 + 2) * ATT_V_ROW + j] = (_Float16)vv.z;
        Vt[(d4 * 4 + 3) * ATT_V_ROW + j] = (_Float16)vv.w;
    }
    // zero pad cols j = 139..143 (read by PV, ps there is 0 but avoid NaN*0)
    for (int i = tid; i < 128 * 5; i += 256) {
        int d = i / 5, jt = SEQS + i % 5;
        Vt[d * ATT_V_ROW + jt] = (_Float16)0.f;
    }
    __syncthreads();

    const float scale = 0.08838834764831845f;
    for (int t = 0; t < 18; ++t) {
        int p = wv + 4 * t;
        if (p >= 70) continue;
        int q0 = 2 * p, q1 = 2 * p + 1;
        bool h1 = q1 < SEQS;
        {
            float2 f0 = *(const float2*)&q[hb + (size_t)q0 * D + lane * 2];
            qs[(wv * 2 + 0) * 64 + lane] = half2_t{(_Float16)f0.x, (_Float16)f0.y};
            if (h1) {
                float2 f1 = *(const float2*)&q[hb + (size_t)q1 * D + lane * 2];
                qs[(wv * 2 + 1) * 64 + lane] = half2_t{(_Float16)f1.x, (_Float16)f1.y};
            }
        }
        float s0[3], s1[3];
#pragma unroll
        for (int jj = 0; jj < 3; ++jj) { s0[jj] = -1e30f; s1[jj] = -1e30f; }
#pragma unroll
        for (int jj = 0; jj < 3; ++jj) {
            int j = lane + jj * 64;
            if (j < SEQS) {
                float a0 = 0, a1 = 0;
                const int jb = j * 128, jx = j & 7;
#pragma unroll
                for (int c = 0; c < 16; ++c) {
                    half8_t kk = *(const half8_t*)(Ksh + jb + ((c ^ jx) << 3));
                    half8_t q0v = *(const half8_t*)(qs + (wv * 2 + 0) * 64 + c * 4);
                    a0 = dot8(kk, q0v, a0);
                    if (h1) {
                        half8_t q1v = *(const half8_t*)(qs + (wv * 2 + 1) * 64 + c * 4);
                        a1 = dot8(kk, q1v, a1);
                    }
                }
                s0[jj] = a0 * scale; s1[jj] = a1 * scale;
            }
        }
        // softmax + write ps (f16)
        {
            float m0 = wmax(fmaxf(fmaxf(s0[0], s0[1]), s0[2]));
            float z0 = 0; float e0[3];
#pragma unroll
            for (int jj = 0; jj < 3; ++jj) {
                int j = lane + jj * 64;
                e0[jj] = (j < SEQS) ? expf(s0[jj] - m0) : 0.f;
                z0 += e0[jj];
            }
            z0 = wsum(z0); float inv0 = 1.f / z0;
#pragma unroll
            for (int jj = 0; jj < 3; ++jj) {
                int j = lane + jj * 64;
                if (j < ATT_PS_ROW) ps[(wv * 2 + 0) * ATT_PS_ROW + j] = (_Float16)(e0[jj] * inv0);
            }
        }
        if (h1) {
            float m1 = wmax(fmaxf(fmaxf(s1[0], s1[1]), s1[2]));
            float z1 = 0; float e1[3];
#pragma unroll
            for (int jj = 0; jj < 3; ++jj) {
                int j = lane + jj * 64;
                e1[jj] = (j < SEQS) ? expf(s1[jj] - m1) : 0.f;
                z1 += e1[jj];
            }
            z1 = wsum(z1); float inv1 = 1.f / z1;
#pragma unroll
            for (int jj = 0; jj < 3; ++jj) {
                int j = lane + jj * 64;
                if (j < ATT_PS_ROW) ps[(wv * 2 + 1) * ATT_PS_ROW + j] = (_Float16)(e1[jj] * inv1);
            }
        }
        // PV: lane owns d = lane, lane+64; V rows shared between q0,q1
        float o00 = 0, o01 = 0, o10 = 0, o11 = 0;
#pragma unroll
        for (int c8 = 0; c8 < 18; ++c8) {
            half8_t va = *(const half8_t*)(Vt + lane * ATT_V_ROW + c8 * 8);
            half8_t vb = *(const half8_t*)(Vt + (lane + 64) * ATT_V_ROW + c8 * 8);
            half8_t p0 = *(const half8_t*)(ps + (wv * 2 + 0) * ATT_PS_ROW + c8 * 8);
            o00 = dot8(va, p0, o00);
            o01 = dot8(vb, p0, o01);
            if (h1) {
                half8_t p1 = *(const half8_t*)(ps + (wv * 2 + 1) * ATT_PS_ROW + c8 * 8);
                o10 = dot8(va, p1, o10);
                o11 = dot8(vb, p1, o11);
            }
        }
        o[hb + (size_t)q0 * D + lane]      = o00;
        o[hb + (size_t)q0 * D + lane + 64] = o01;
        if (h1) {
            o[hb + (size_t)q1 * D + lane]      = o10;
            o[hb + (size_t)q1 * D + lane + 64] = o11;
        }
    }
}

__global__ void ring_pick(const float* __restrict__ t, float* __restrict__ rv) {
    int i = blockIdx.x * 256 + threadIdx.x;
    if (i >= RGS * D) return;
    int r = i >> 9, d = i & 511;
    const float* p = &t[(size_t)r * RS * D + d];
    float best = p[0], ba = fabsf(best);
#pragma unroll
    for (int s = 1; s < RS; ++s) {
        float x = p[(size_t)s * D];
        float ax = fabsf(x);
        if (ax > ba) { ba = ax; best = x; }
    }
    rv[i] = best;
}

__global__ void assemble(const float* __restrict__ h, const float* __restrict__ rv,
                         const float* __restrict__ cls, const float* __restrict__ ringt,
                         const float* __restrict__ endt, float* __restrict__ seq) {
    int i = blockIdx.x * 256 + threadIdx.x;
    if (i >= NSEQ * D) return;
    int row = i >> 9, d = i & 511;
    int b = row / SEQS, p = row % SEQS;
    float val;
    if (p == 0)        val = cls[d];
    else if (p <= 128) val = h[((size_t)b * 128 + (p - 1)) * D + d];
    else if (p == 129) val = ringt[d];
    else if (p <= 137) val = rv[((size_t)b * 8 + (p - 130)) * D + d];
    else               val = endt[d];
    seq[i] = val;
}

// ---------------------------------------------------------------------------
extern "C" void kernel_launch(void* const* d_in, const int* in_sizes, int n_in,
                              void* d_out, int out_size, void* d_ws, size_t ws_size,
                              hipStream_t stream) {
    (void)in_sizes; (void)n_in; (void)out_size; (void)ws_size;

    const float* x          = (const float*)d_in[0];
    const float* edge_attr  = (const float*)d_in[1];
    const int*   ei         = (const int*)  d_in[2];
    const int*   rings_idx  = (const int*)  d_in[3];
    const float* x_proj_w   = (const float*)d_in[8];
    const float* x_proj_b   = (const float*)d_in[9];
    const float* e_proj_w   = (const float*)d_in[10];
    const float* e_proj_b   = (const float*)d_in[11];
    const float* gat_wl     = (const float*)d_in[12];
    const float* gat_bl     = (const float*)d_in[13];
    const float* gat_wr     = (const float*)d_in[14];
    const float* gat_br     = (const float*)d_in[15];
    const float* gat_we     = (const float*)d_in[16];
    const float* gat_att    = (const float*)d_in[17];
    const float* gat_bias   = (const float*)d_in[18];
    const float* gat_ln     = (const float*)d_in[19];
    const float* ring_attn_w= (const float*)d_in[20];
    const float* ring_attn_b= (const float*)d_in[21];
    const float* ring_w1    = (const float*)d_in[22];
    const float* ring_b1    = (const float*)d_in[23];
    const float* ring_w2    = (const float*)d_in[24];
    const float* ring_b2    = (const float*)d_in[25];
    const float* ring_ln    = (const float*)d_in[26];
    const float* mol_attn_w = (const float*)d_in[27];
    const float* mol_attn_b = (const float*)d_in[28];
    const float* mol_w1     = (const float*)d_in[29];
    const float* mol_b1     = (const float*)d_in[30];
    const float* mol_w2     = (const float*)d_in[31];
    const float* mol_b2     = (const float*)d_in[32];
    const float* mol_ln     = (const float*)d_in[33];
    const float* cls_tok    = (const float*)d_in[34];
    const float* ring_tok   = (const float*)d_in[35];
    const float* end_tok    = (const float*)d_in[36];

    constexpr size_t MB = 1024 * 1024;
    char* wsb = (char*)d_ws;
#define WSF(off) ((float*)(wsb + (size_t)(off)))
#define WSI(off) ((int*)(wsb + (size_t)(off)))
#define WSU(off) ((unsigned short*)(wsb + (size_t)(off)))

    // ---- GAT phase ----
    float* H    = WSF(0);                 // persists through assemble
    float* XL   = WSF(16 * MB);
    float* XR   = WSF(32 * MB);
    float* HN   = WSF(48 * MB);
    float* EIN  = WSF(64 * MB);
    float* WE17 = WSF(67 * MB);           // [6][17][512]
    float* AGG  = WSF(68 * MB);
    int*   DEGI = WSI(68 * MB + 512 * 1024);
    int*   OFF  = WSI(68 * MB + 576 * 1024);
    int*   CNT  = WSI(68 * MB + 640 * 1024);
    int*   ADJ  = WSI(68 * MB + 704 * 1024);
    float* RVEC = WSF(70 * MB);           // persists into mol phase

    // ---- ring phase ----
    float* T    = WSF(71 * MB);
    float* RQ   = WSF(77 * MB);
    float* RK   = WSF(83 * MB);
    float* RV   = WSF(89 * MB);
    float* RO   = WSF(95 * MB);
    float* OP   = WSF(101 * MB);          // [2][3072][512] O-gemm partials
    float* RY   = WSF(113 * MB);
    float* RFF  = WSF(119 * MB);          // [3072][2048]
    float* W2P  = WSF(143 * MB);          // [4][3072][512] W2 partials
    float* RT2  = WSF(167 * MB);

    // ---- mol phase ----
    float* SEQ  = WSF(71 * MB);
    float* MQKV = WSF(89 * MB);           // [3][8960][512]
    float* MO   = WSF(142 * MB);
    unsigned short* ACTh = WSU(161 * MB);
    unsigned short* ACTl = WSU(170 * MB);
    unsigned short* WQKVh = WSU(179 * MB);  // [3][512][512]
    unsigned short* WQKVl = WSU(181 * MB);
    unsigned short* WOh  = WSU(183 * MB);
    unsigned short* WOl  = WSU(183 * MB + 512 * 1024);
    unsigned short* W1h  = WSU(184 * MB);
    unsigned short* W1l  = WSU(186 * MB);
    unsigned short* W2h  = WSU(188 * MB);
    unsigned short* W2l  = WSU(190 * MB);
    float* MTMP = WSF(89 * MB);           // over MQKV (dead after attn)
    float* MY   = WSF(107 * MB);
    unsigned short* MFFh = WSU(125 * MB); // [8960][2048]
    unsigned short* MFFl = WSU(16 * MB);  // over XL/XR/HN (dead)
    float* MT2  = WSF(71 * MB);           // over SEQ (dead)

    dim3 blk(256);
    auto gemm1 = [&](const float* A, const float* B, const float* bias, float* C,
                     int M, int Nc, int K, int flags) {
        GB g{A, B, nullptr, nullptr, bias, nullptr, nullptr, C, nullptr, nullptr,
             M, Nc, K, flags, 1, K, 0};
        gemm_f32b<<<dim3(M / 128, Nc / 128, 1), blk, 0, stream>>>(g);
    };

    // ---- phase 0: graph preprocessing + all-layer WE17 ----
    hipMemsetAsync(DEGI, 0, NN * 4, stream);
    hipMemsetAsync(CNT, 0, NN * 4, stream);
    hipMemsetAsync(AGG, 0, (size_t)NN * 16 * 4, stream);
    hipMemsetAsync(WE17, 0, (size_t)6 * 17 * D * 4, stream);
    deg_int<<<EE / 256, blk, 0, stream>>>(ei, DEGI);
    scan_deg<<<1, blk, 0, stream>>>(DEGI, OFF);
    csr_fill<<<EE / 256, blk, 0, stream>>>(ei, CNT, OFF, ADJ);
    eagg_acc<<<EE * 16 / 256, blk, 0, stream>>>(edge_attr, ei, AGG);
    ein_build<<<ENL / 256, blk, 0, stream>>>(edge_attr, AGG, DEGI, EIN);
    we17_build<<<dim3(2, 4, 6), blk, 0, stream>>>(e_proj_w, e_proj_b, gat_we, WE17);

    // ---- phase 1: x projection ----
    gemm1(x, x_proj_w, x_proj_b, H, NN, D, 64, 1);

    // ---- phase 2: 6x GATv2 (f32) ----
    for (int l = 0; l < 6; ++l) {
        GB g{H, gat_wl + (size_t)l * D * D, gat_wr + (size_t)l * D * D, nullptr,
             gat_bl + l * D, gat_br + l * D, nullptr,
             XL, XR, nullptr, NN, D, D, 1, 1, D, 0};
        gemm_f32b<<<dim3(NN / 128, D / 128, 2), blk, 0, stream>>>(g);
        gat_node<<<NN / 4, blk, 0, stream>>>(XL, XR, EIN, WE17 + (size_t)l * 17 * D,
                                             OFF, ADJ, ei, gat_att + l * D, HN);
        if (l < 5) {
            ln_rows<<<NN / 4, blk, 0, stream>>>(HN, nullptr, gat_bias + l * D,
                gat_ln + (size_t)l * 2 * D, gat_ln + (size_t)l * 2 * D + D, H, NN, 3, 1);
        } else {
            ln_rows<<<NN / 4, blk, 0, stream>>>(HN, nullptr, gat_bias + l * D,
                nullptr, nullptr, H, NN, 0, 1);
        }
    }

    // ---- phase 3: ring encoder (f32) ----
    const int RROWS = RGS * RS;  // 3072
    gather_rows<<<RROWS * D / 256, blk, 0, stream>>>(H, rings_idx, T, RROWS);
    {   // QKV batched (z=3)
        GB g{T, ring_attn_w + 0 * D * D, ring_attn_w + 1 * D * D, ring_attn_w + 2 * D * D,
             ring_attn_b + 0 * D, ring_attn_b + 1 * D, ring_attn_b + 2 * D,
             RQ, RK, RV, RROWS, D, D, 1, 1, D, 0};
        gemm_f32b<<<dim3(RROWS / 128, D / 128, 3), blk, 0, stream>>>(g);
    }
    ring_attn<<<RGS * 2, blk, 0, stream>>>(RQ, RK, RV, RO);
    {   // O projection split-K=2 -> partials, bias folded in ln
        GB g{RO, ring_attn_w + 3 * D * D, nullptr, nullptr, nullptr, nullptr, nullptr,
             OP, nullptr, nullptr, RROWS, D, D, 0, 2, 256, (long long)RROWS * D};
        gemm_f32b<<<dim3(RROWS / 128, D / 128, 2), blk, 0, stream>>>(g);
    }
    ln_rows<<<RROWS / 4, blk, 0, stream>>>(OP, T, ring_attn_b + 3 * D,
                                           ring_ln, ring_ln + D, RY, RROWS, 2, 2);
    gemm1(RY, ring_w1, ring_b1, RFF, RROWS, DFF, D, 3);
    {   // W2 split-K=4
        GB g{RFF, ring_w2, nullptr, nullptr, nullptr, nullptr, nullptr,
             W2P, nullptr, nullptr, RROWS, D, DFF, 0, 4, 512, (long long)RROWS * D};
        gemm_f32b<<<dim3(RROWS / 128, D / 128, 4), blk, 0, stream>>>(g);
    }
    ln_rows<<<RROWS / 4, blk, 0, stream>>>(W2P, RY, ring_b2,
                                           ring_ln + 2 * D, ring_ln + 3 * D, RT2, RROWS, 2, 4);
    ring_pick<<<RGS * D / 256, blk, 0, stream>>>(RT2, RVEC);

    // ---- phase 4: mol encoder (MFMA bf16x3 + fused f16 attention) ----
    assemble<<<(NSEQ * D) / 256, blk, 0, stream>>>(H, RVEC, cls_tok, ring_tok, end_tok, SEQ);
    for (int z = 0; z < 3; ++z)
        wsplitT<<<(D * D + 255) / 256, blk, 0, stream>>>(
            mol_attn_w + (size_t)z * D * D, WQKVh + (size_t)z * D * D, WQKVl + (size_t)z * D * D, D, D);
    wsplitT<<<(D * D + 255) / 256, blk, 0, stream>>>(mol_attn_w + 3 * (size_t)D * D, WOh, WOl, D, D);
    wsplitT<<<(D * DFF + 255) / 256, blk, 0, stream>>>(mol_w1, W1h, W1l, D, DFF);
    wsplitT<<<(DFF * D + 255) / 256, blk, 0, stream>>>(mol_w2, W2h, W2l, DFF, D);

    const int N4_512 = MHAT * D / 4;
    float* MQ = MQKV;
    float* MK = MQKV + (size_t)MHAT * D;
    float* MV = MQKV + 2 * (size_t)MHAT * D;
    asplit4<<<(N4_512 + 255) / 256, blk, 0, stream>>>(SEQ, ACTh, ACTl, N4_512);
    gemm_split3<<<dim3(MHAT / 128, D / 128, 3), blk, 0, stream>>>(
        ACTh, ACTl, WQKVh, WQKVl, mol_attn_b, MQKV, nullptr, nullptr,
        D, D, 1, (long long)D * D, (long long)MHAT * D, D);

    hipFuncSetAttribute(reinterpret_cast<const void*>(mol_attn3),
                        hipFuncAttributeMaxDynamicSharedMemorySize, ATT_SMEM);
    mol_attn3<<<BMOL * 4, blk, ATT_SMEM, stream>>>(MQ, MK, MV, MO);

    asplit4<<<(N4_512 + 255) / 256, blk, 0, stream>>>(MO, ACTh, ACTl, N4_512);
    gemm_split3<<<dim3(MHAT / 128, D / 128, 1), blk, 0, stream>>>(
        ACTh, ACTl, WOh, WOl, mol_attn_b + 3 * D, MTMP, nullptr, nullptr, D, D, 1, 0, 0, 0);
    ln_rows<<<(NSEQ + 3) / 4, blk, 0, stream>>>(MTMP, SEQ, nullptr,
                                                mol_ln, mol_ln + D, MY, NSEQ, 2, 1);
    asplit4<<<(N4_512 + 255) / 256, blk, 0, stream>>>(MY, ACTh, ACTl, N4_512);
    gemm_split3<<<dim3(MHAT / 128, DFF / 128, 1), blk, 0, stream>>>(
        ACTh, ACTl, W1h, W1l, mol_b1, nullptr, MFFh, MFFl, DFF, D, 1 | 2 | 4, 0, 0, 0);
    gemm_split3<<<dim3(MHAT / 128, D / 128, 1), blk, 0, stream>>>(
        MFFh, MFFl, W2h, W2l, mol_b2, MT2, nullptr, nullptr, D, DFF, 1, 0, 0, 0);

    float* outf = (float*)d_out;
    ln_rows<<<(NSEQ + 3) / 4, blk, 0, stream>>>(MT2, MY, nullptr,
                                                mol_ln + 2 * D, mol_ln + 3 * D, outf, NSEQ, 2, 1);
    fill_f32<<<(BMOL * 128 + BMOL * 8 + 255) / 256, blk, 0, stream>>>(
        outf + (size_t)NSEQ * D, 1.0f, BMOL * 128 + BMOL * 8);
}